// Round 5
// baseline (361.355 us; speedup 1.0000x reference)
//
#include <hip/hip_runtime.h>
#include <stdint.h>

typedef unsigned short u16;
typedef __attribute__((ext_vector_type(8))) __bf16 bf16x8;
typedef __attribute__((ext_vector_type(4))) float f32x4;

#define DEVI __device__ __forceinline__

DEVI u16 f32_to_bf16(float f) {
  uint32_t u = __builtin_bit_cast(uint32_t, f);
  u += 0x7FFFu + ((u >> 16) & 1u);   // RNE; inputs are never NaN here
  return (u16)(u >> 16);
}

DEVI void gl2lds16(const void* g, void* l) {
  __builtin_amdgcn_global_load_lds(
      (const __attribute__((address_space(1))) void*)g,
      (__attribute__((address_space(3))) void*)l, 16, 0, 0);
}

// S is packed triangular: per batch, strip rt (128 rows) has row stride
// (rt+1)*128 and begins at tri(rt)*16384 u16.  Per-batch size 136*16384 u16.
#define S_BATCH 2228224  // u16 elements per batch = 136*16384

// ---------------------------------------------------------------------------
__global__ void cast_f32_to_bf16_kernel(const float* __restrict__ src,
                                        u16* __restrict__ dst, int n4) {
  int i = blockIdx.x * blockDim.x + threadIdx.x;
  const int stride = gridDim.x * blockDim.x;
  for (; i < n4; i += stride) {
    const float4 v = ((const float4*)src)[i];
    ushort4 o;
    o.x = f32_to_bf16(v.x);
    o.y = f32_to_bf16(v.y);
    o.z = f32_to_bf16(v.z);
    o.w = f32_to_bf16(v.w);
    ((ushort4*)dst)[i] = o;
  }
}

// weights -> contiguous bf16 [3][1024][1024]; z==3 zero-inits sums[16384].
__global__ void cast_w_kernel(const float* __restrict__ wq,
                              const float* __restrict__ wk,
                              const float* __restrict__ wv,
                              u16* __restrict__ wb, float* __restrict__ sums) {
  const int z = blockIdx.y;
  if (z == 3) {
    int i = blockIdx.x * blockDim.x + threadIdx.x;
    if (i < 4096) ((float4*)sums)[i] = (float4){0.f, 0.f, 0.f, 0.f};
    return;
  }
  const float* src = (z == 0) ? wq : (z == 1) ? wk : wv;
  u16* dst = wb + (size_t)z * 1048576;
  int i = blockIdx.x * blockDim.x + threadIdx.x;
  const int stride = gridDim.x * blockDim.x;
  for (; i < 262144; i += stride) {
    const float4 v = ((const float4*)src)[i];
    ushort4 o;
    o.x = f32_to_bf16(v.x);
    o.y = f32_to_bf16(v.y);
    o.z = f32_to_bf16(v.z);
    o.w = f32_to_bf16(v.w);
    ((ushort4*)dst)[i] = o;
  }
}

// ---------------------------------------------------------------------------
// Fused Q/K/V projection — 256x256-tile, 8-wave, 8-phase schedule (T3+T4+T5).
// ROUND-3 VERSION (measured 106.6 us / MfmaUtil 40.6%) — persistent variant
// regressed (r4: +4us steady, +20MB FETCH/WRITE, 213us cold dispatch).
// ---------------------------------------------------------------------------
__global__ __launch_bounds__(512, 2) void qkv_kernel(
    const u16* __restrict__ xb, const u16* __restrict__ wb,
    const float* __restrict__ bq, const float* __restrict__ bk,
    const float* __restrict__ bv, u16* __restrict__ Qb, u16* __restrict__ Kb,
    u16* __restrict__ Vt) {
  __shared__ __align__(16) u16 lds[65536];  // 128 KB

  const int id = blockIdx.x;                 // 0..767
  const int wg = (id & 7) * 96 + (id >> 3);  // bijective XCD swizzle (768%8==0)
  const int g = wg >> 3, u = wg & 7;         // groups of 8 tiles: 4c x 2t (~3MB L2)
  const int z = g >> 5;                      // 0..2
  const int tp = g & 31;                     // t-pair
  const int tmt = tp * 2 + (u >> 2);         // t-tile 0..63
  const int tct = u & 3;                     // c-tile 0..3

  // Q/K: A=W (m=c, reg-quad packs c); V: A=x (m=t, reg-quad packs t).
  int m0, n0;
  const u16* Aptr;
  const u16* Bptr;
  if (z < 2) {
    m0 = tct * 256;
    n0 = tmt * 256;
    Aptr = wb + (size_t)z * 1048576 + (size_t)m0 * 1024;
    Bptr = xb + (size_t)n0 * 1024;
  } else {
    m0 = tmt * 256;
    n0 = tct * 256;
    Aptr = xb + (size_t)m0 * 1024;
    Bptr = wb + (size_t)2 * 1048576 + (size_t)n0 * 1024;
  }

  const int tid = threadIdx.x;
  const int srow = tid >> 3;                 // staged row 0..63 (+64 2nd load)
  const int sgrp = ((tid & 7) - srow) & 7;   // rotated source column-group
  const u16* Ag = Aptr + (size_t)srow * 1024 + sgrp * 8;
  const u16* Bg = Bptr + (size_t)srow * 1024 + sgrp * 8;
  char* ldsDst = (char*)lds + tid * 16;

  // Half-tile stagers: 2 x gl_lds x 16B per thread = 128 rows x 64 cols bf16.
#define ST_A0(kt) do { const u16* s_ = Ag + (kt) * 64;           char* d_ = ldsDst + (((kt) & 1) * 65536);         gl2lds16(s_, d_); gl2lds16(s_ + 65536, d_ + 8192); } while (0)
#define ST_A1(kt) do { const u16* s_ = Ag + 131072 + (kt) * 64;  char* d_ = ldsDst + (((kt) & 1) * 65536) + 16384; gl2lds16(s_, d_); gl2lds16(s_ + 65536, d_ + 8192); } while (0)
#define ST_B0(kt) do { const u16* s_ = Bg + (kt) * 64;           char* d_ = ldsDst + (((kt) & 1) * 65536) + 32768; gl2lds16(s_, d_); gl2lds16(s_ + 65536, d_ + 8192); } while (0)
#define ST_B1(kt) do { const u16* s_ = Bg + 131072 + (kt) * 64;  char* d_ = ldsDst + (((kt) & 1) * 65536) + 49152; gl2lds16(s_, d_); gl2lds16(s_ + 65536, d_ + 8192); } while (0)

  // Prologue: K-tile 0 complete + A0/B0/B1 of K-tile 1 (7 half-tiles).
  ST_A0(0); ST_B0(0); ST_B1(0); ST_A1(0);
  ST_A0(1); ST_B0(1); ST_B1(1);

  const int lane = tid & 63, wid = tid >> 6;
  const int wr = wid >> 2, wc = wid & 3;
  const int l15 = lane & 15, quad = lane >> 4;

  int aoff[4][2], boff[2][2];
#pragma unroll
  for (int i_ = 0; i_ < 4; ++i_) {
    const int arow = wr * 64 + i_ * 16 + l15;
#pragma unroll
    for (int k_ = 0; k_ < 2; ++k_)
      aoff[i_][k_] = arow * 64 + ((k_ * 4 + quad + arow) & 7) * 8;
  }
#pragma unroll
  for (int j_ = 0; j_ < 2; ++j_) {
    const int brow = wc * 32 + j_ * 16 + l15;
#pragma unroll
    for (int k_ = 0; k_ < 2; ++k_)
      boff[j_][k_] = brow * 64 + ((k_ * 4 + quad + brow) & 7) * 8;
  }

  f32x4 acc[2][2][4][2];
#pragma unroll
  for (int a_ = 0; a_ < 2; ++a_)
#pragma unroll
    for (int b_ = 0; b_ < 2; ++b_)
#pragma unroll
      for (int i_ = 0; i_ < 4; ++i_)
#pragma unroll
        for (int j_ = 0; j_ < 2; ++j_)
          acc[a_][b_][i_][j_] = (f32x4){0.f, 0.f, 0.f, 0.f};

  bf16x8 af[4][2], bfr[2][2][2];

#define LOADA(qm, buf) do { const u16* p_ = lds + (buf) * 32768 + (qm) * 8192; \
  _Pragma("unroll") for (int i_ = 0; i_ < 4; ++i_) \
  _Pragma("unroll") for (int k_ = 0; k_ < 2; ++k_) \
    af[i_][k_] = *(const bf16x8*)(p_ + aoff[i_][k_]); } while (0)
#define LOADB(qn, buf) do { const u16* p_ = lds + (buf) * 32768 + 16384 + (qn) * 8192; \
  _Pragma("unroll") for (int j_ = 0; j_ < 2; ++j_) \
  _Pragma("unroll") for (int k_ = 0; k_ < 2; ++k_) \
    bfr[qn][j_][k_] = *(const bf16x8*)(p_ + boff[j_][k_]); } while (0)
#define MMA(qm, qn) do { \
  _Pragma("unroll") for (int i_ = 0; i_ < 4; ++i_) \
  _Pragma("unroll") for (int j_ = 0; j_ < 2; ++j_) \
  _Pragma("unroll") for (int k_ = 0; k_ < 2; ++k_) \
    acc[qm][qn][i_][j_] = __builtin_amdgcn_mfma_f32_16x16x32_bf16( \
        af[i_][k_], bfr[qn][j_][k_], acc[qm][qn][i_][j_], 0, 0, 0); } while (0)

#define BAR __builtin_amdgcn_s_barrier()
#define WLG0 asm volatile("s_waitcnt lgkmcnt(0)")
#define WLG8 asm volatile("s_waitcnt lgkmcnt(8)")
#define PRIO1 __builtin_amdgcn_s_setprio(1)
#define PRIO0 __builtin_amdgcn_s_setprio(0)
#define WVM6 asm volatile("s_waitcnt vmcnt(6)" ::: "memory")
#define WVM0 asm volatile("s_waitcnt vmcnt(0)" ::: "memory")

  WVM6;  // K-tile 0 landed
  BAR;

#pragma unroll 1
  for (int it = 0; it < 7; ++it) {
    const int j0 = 2 * it;
    // P1 (0,0) buf0
    LOADA(0, 0); LOADB(0, 0); ST_A1(j0 + 1); WLG8;
    BAR; WLG0; PRIO1; MMA(0, 0); PRIO0; BAR;
    // P2 (0,1)
    LOADB(1, 0); ST_A0(j0 + 2);
    BAR; WLG0; PRIO1; MMA(0, 1); PRIO0; BAR;
    // P3 (1,1)
    LOADA(1, 0); ST_B0(j0 + 2);
    BAR; WLG0; PRIO1; MMA(1, 1); PRIO0; BAR;
    // P4 (1,0)
    ST_B1(j0 + 2);
    BAR; PRIO1; MMA(1, 0); PRIO0;
    WVM6;  // K-tile j0+1 landed
    BAR;
    // P5 (0,0) buf1
    LOADA(0, 1); LOADB(0, 1); ST_A1(j0 + 2); WLG8;
    BAR; WLG0; PRIO1; MMA(0, 0); PRIO0; BAR;
    // P6 (0,1)
    LOADB(1, 1); ST_A0(j0 + 3);
    BAR; WLG0; PRIO1; MMA(0, 1); PRIO0; BAR;
    // P7 (1,1)
    LOADA(1, 1); ST_B0(j0 + 3);
    BAR; WLG0; PRIO1; MMA(1, 1); PRIO0; BAR;
    // P8 (1,0)
    ST_B1(j0 + 3);
    BAR; PRIO1; MMA(1, 0); PRIO0;
    WVM6;  // K-tile j0+2 landed
    BAR;
  }
  {  // it = 7: K-tiles 14 (buf0) / 15 (buf1); only A1(15) left to stage
    LOADA(0, 0); LOADB(0, 0); ST_A1(15); WLG8;
    BAR; WLG0; PRIO1; MMA(0, 0); PRIO0; BAR;
    LOADB(1, 0);
    BAR; WLG0; PRIO1; MMA(0, 1); PRIO0; BAR;
    LOADA(1, 0);
    BAR; WLG0; PRIO1; MMA(1, 1); PRIO0; BAR;
    BAR; PRIO1; MMA(1, 0); PRIO0;
    WVM0;  // drain: K-tile 15 landed
    BAR;
    LOADA(0, 1); LOADB(0, 1); WLG8;
    BAR; WLG0; PRIO1; MMA(0, 0); PRIO0; BAR;
    LOADB(1, 1);
    BAR; WLG0; PRIO1; MMA(0, 1); PRIO0; BAR;
    LOADA(1, 1);
    BAR; WLG0; PRIO1; MMA(1, 1); PRIO0; BAR;
    PRIO1; MMA(1, 0); PRIO0;
    BAR;  // mainloop done; LDS reusable
  }

  // Epilogue: per N-half th, stage [128 n-rows][256 m-cols] (+8 pad) in LDS,
  // then full-line 16B/lane global stores.
  if (z < 2) {
    const float* bias = (z == 0) ? bq : bk;
    u16* Out = (z == 0) ? Qb : Kb;
#pragma unroll
    for (int th = 0; th < 2; ++th) {
      if (th) __syncthreads();
#pragma unroll
      for (int qm = 0; qm < 2; ++qm)
#pragma unroll
        for (int i_ = 0; i_ < 4; ++i_) {
          const int c = qm * 128 + wr * 64 + i_ * 16 + quad * 4;
          const float4 b4 = *(const float4*)(bias + m0 + c);
#pragma unroll
          for (int j_ = 0; j_ < 2; ++j_) {
            const int row = wc * 32 + j_ * 16 + l15;
            ushort4 o;
            o.x = f32_to_bf16(acc[qm][th][i_][j_][0] + b4.x);
            o.y = f32_to_bf16(acc[qm][th][i_][j_][1] + b4.y);
            o.z = f32_to_bf16(acc[qm][th][i_][j_][2] + b4.z);
            o.w = f32_to_bf16(acc[qm][th][i_][j_][3] + b4.w);
            *(ushort4*)(lds + row * 264 + c) = o;   // [t][c]
          }
        }
      __syncthreads();
#pragma unroll
      for (int p = 0; p < 8; ++p) {
        const int row = p * 16 + (tid >> 5);
        const int c0 = (tid & 31) * 8;
        const uint4 v = *(const uint4*)(lds + row * 264 + c0);
        *(uint4*)(Out + (size_t)(n0 + th * 128 + row) * 1024 + m0 + c0) = v;
      }
    }
  } else {
    const int b = m0 >> 11;
    const int t0b = m0 & 2047;
    u16* Out = Vt + (size_t)b * 2097152;
#pragma unroll
    for (int th = 0; th < 2; ++th) {
      if (th) __syncthreads();
#pragma unroll
      for (int j_ = 0; j_ < 2; ++j_) {
        const int row = wc * 32 + j_ * 16 + l15;      // c within half
        const float bb = bv[n0 + th * 128 + row];
#pragma unroll
        for (int qm = 0; qm < 2; ++qm)
#pragma unroll
          for (int i_ = 0; i_ < 4; ++i_) {
            const int c = qm * 128 + wr * 64 + i_ * 16 + quad * 4;  // t
            ushort4 o;
            o.x = f32_to_bf16(acc[qm][th][i_][j_][0] + bb);
            o.y = f32_to_bf16(acc[qm][th][i_][j_][1] + bb);
            o.z = f32_to_bf16(acc[qm][th][i_][j_][2] + bb);
            o.w = f32_to_bf16(acc[qm][th][i_][j_][3] + bb);
            *(ushort4*)(lds + row * 264 + c) = o;     // [c][t]
          }
      }
      __syncthreads();
#pragma unroll
      for (int p = 0; p < 8; ++p) {
        const int row = p * 16 + (tid >> 5);
        const int c0 = (tid & 31) * 8;
        const uint4 v = *(const uint4*)(lds + row * 264 + c0);
        *(uint4*)(Out + (size_t)(n0 + th * 128 + row) * 2048 + t0b + c0) = v;
      }
    }
  }
#undef ST_A0
#undef ST_A1
#undef ST_B0
#undef ST_B1
#undef LOADA
#undef LOADB
#undef MMA
#undef BAR
#undef WLG0
#undef WLG8
#undef PRIO1
#undef PRIO0
#undef WVM6
#undef WVM0
}

// ---------------------------------------------------------------------------
// Scores — 256(s) x 128(t) tile, 8 waves, 2 phases/K-tile, phase-head loads.
// LDS 80KB (= 160/2): A0/A1 double-buffered (4x16KB) + SINGLE-buffered B
// (16KB) -> 2 blocks/CU for inter-block stall overlap.  Safe because bfr is
// register-cached at Q1-head (used by both Q1 and Q2 MFMAs), so the B region
// is dead after Q1's reads; ST_B(j+1) issues at Q2-head (one full
// barrier+MFMA after the readers — same separation as every other ST).
// vmcnt ledger: per K-tile {Q1: ST_A1(j+1)} {Q2: ST_B(j+1), ST_A0(j+2),
// WVM2} — WVM2 leaves only the newest ST outstanding => A0/A1/B of tile j+1
// landed at Q1(j+1) entry.  Region map (u16 offs): A0_b0@0, A0_b1@8192,
// A1_b0@16384, A1_b1@24576, B@32768.
// ---------------------------------------------------------------------------
__global__ __launch_bounds__(512, 4) void score_kernel(const u16* __restrict__ Kb,
                                                       const u16* __restrict__ Qb,
                                                       u16* __restrict__ Spk,
                                                       float* __restrict__ sums) {
  __shared__ __align__(16) u16 lds[40960];  // 80 KB

  const int id = blockIdx.x;   // 0..575
  const int b = id & 7;        // batch per XCD: K/Q tiles stay in XCD L2
  const int l = id >> 3;       // 0..71
  int k = (int)((sqrtf(4.f * l + 1.f) - 1.f) * 0.5f);
  if (k * (k + 1) > l) --k;
  if ((k + 1) * (k + 2) <= l) ++k;
  const int off = l - k * (k + 1);
  const int hi = (off >= (k + 1));
  const int rt = 2 * k + hi;           // t-strip 0..15 (128 rows)
  const int ct = off - (hi ? (k + 1) : 0);  // s-tile 0..k (256 cols)
  const bool maskT = (ct == k);        // only the last s-tile crosses diag

  const int tid = threadIdx.x;
  const int srow = tid >> 3;
  const int sgrp = ((tid & 7) - srow) & 7;
  const u16* A = Qb + ((size_t)b * 2048 + ct * 256) * 1024;  // 256 s-rows
  const u16* B = Kb + ((size_t)b * 2048 + rt * 128) * 1024;  // 128 t-rows
  const u16* Ag = A + (size_t)srow * 1024 + sgrp * 8;
  const u16* Bg = B + (size_t)srow * 1024 + sgrp * 8;
  char* ldsDst = (char*)lds + tid * 16;

#define ST_A0(kt) do { const u16* s_ = Ag + (kt) * 64;           char* d_ = ldsDst + (((kt) & 1) * 16384);         gl2lds16(s_, d_); gl2lds16(s_ + 65536, d_ + 8192); } while (0)
#define ST_A1(kt) do { const u16* s_ = Ag + 131072 + (kt) * 64;  char* d_ = ldsDst + 32768 + (((kt) & 1) * 16384); gl2lds16(s_, d_); gl2lds16(s_ + 65536, d_ + 8192); } while (0)
#define ST_B(kt)  do { const u16* s_ = Bg + (kt) * 64;           char* d_ = ldsDst + 65536;                        gl2lds16(s_, d_); gl2lds16(s_ + 65536, d_ + 8192); } while (0)

  // Prologue: K-tile 0 complete + A0 of K-tile 1 (B single: can't prestage).
  ST_A0(0); ST_B(0); ST_A1(0); ST_A0(1);

  const int lane = tid & 63, wid = tid >> 6;
  const int wr = wid >> 2, wc = wid & 3;
  const int l15 = lane & 15, quad = lane >> 4;

  int aoff[4][2], boff[2][2];
#pragma unroll
  for (int i_ = 0; i_ < 4; ++i_) {
    const int arow = wr * 64 + i_ * 16 + l15;
#pragma unroll
    for (int k_ = 0; k_ < 2; ++k_)
      aoff[i_][k_] = arow * 64 + ((k_ * 4 + quad + arow) & 7) * 8;
  }
#pragma unroll
  for (int j_ = 0; j_ < 2; ++j_) {
    const int brow = wc * 32 + j_ * 16 + l15;
#pragma unroll
    for (int k_ = 0; k_ < 2; ++k_)
      boff[j_][k_] = brow * 64 + ((k_ * 4 + quad + brow) & 7) * 8;
  }

  f32x4 acc[2][4][2];
#pragma unroll
  for (int q_ = 0; q_ < 2; ++q_)
#pragma unroll
    for (int i_ = 0; i_ < 4; ++i_)
#pragma unroll
      for (int j_ = 0; j_ < 2; ++j_)
        acc[q_][i_][j_] = (f32x4){0.f, 0.f, 0.f, 0.f};

  bf16x8 af[4][2], bfr[2][2];

#define SLOADA(qm, buf) do { const u16* p_ = lds + (qm) * 16384 + (buf) * 8192; \
  _Pragma("unroll") for (int i_ = 0; i_ < 4; ++i_) \
  _Pragma("unroll") for (int k_ = 0; k_ < 2; ++k_) \
    af[i_][k_] = *(const bf16x8*)(p_ + aoff[i_][k_]); } while (0)
#define SLOADB do { const u16* p_ = lds + 32768; \
  _Pragma("unroll") for (int j_ = 0; j_ < 2; ++j_) \
  _Pragma("unroll") for (int k_ = 0; k_ < 2; ++k_) \
    bfr[j_][k_] = *(const bf16x8*)(p_ + boff[j_][k_]); } while (0)
#define SMMA(qm) do { \
  _Pragma("unroll") for (int i_ = 0; i_ < 4; ++i_) \
  _Pragma("unroll") for (int j_ = 0; j_ < 2; ++j_) \
  _Pragma("unroll") for (int k_ = 0; k_ < 2; ++k_) \
    acc[qm][i_][j_] = __builtin_amdgcn_mfma_f32_16x16x32_bf16( \
        af[i_][k_], bfr[j_][k_], acc[qm][i_][j_], 0, 0, 0); } while (0)

#define BAR __builtin_amdgcn_s_barrier()
#define WLG0 asm volatile("s_waitcnt lgkmcnt(0)")
#define PRIO1 __builtin_amdgcn_s_setprio(1)
#define PRIO0 __builtin_amdgcn_s_setprio(0)
#define WVM2 asm volatile("s_waitcnt vmcnt(2)" ::: "memory")
#define WVM0 asm volatile("s_waitcnt vmcnt(0)" ::: "memory")

  WVM2;  // K-tile 0 landed (A0(1) may be in flight)
  BAR;

#pragma unroll 1
  for (int it = 0; it < 7; ++it) {
    const int j0 = 2 * it;
    // Q1(j0) buf0
    SLOADA(0, 0); SLOADB; ST_A1(j0 + 1);
    BAR; WLG0; PRIO1; SMMA(0); PRIO0; BAR;
    // Q2(j0)
    SLOADA(1, 0); ST_B(j0 + 1); ST_A0(j0 + 2);
    BAR; WLG0; PRIO1; SMMA(1); PRIO0;
    WVM2;  // tile j0+1 regions landed (only A0(j0+2) outstanding)
    BAR;
    // Q1(j0+1) buf1
    SLOADA(0, 1); SLOADB; ST_A1(j0 + 2);
    BAR; WLG0; PRIO1; SMMA(0); PRIO0; BAR;
    // Q2(j0+1)
    SLOADA(1, 1); ST_B(j0 + 2); ST_A0(j0 + 3);
    BAR; WLG0; PRIO1; SMMA(1); PRIO0;
    WVM2;  // tile j0+2 regions landed
    BAR;
  }
  {  // tail: K-tiles 14 (buf0), 15 (buf1)
    SLOADA(0, 0); SLOADB; ST_A1(15);
    BAR; WLG0; PRIO1; SMMA(0); PRIO0; BAR;
    SLOADA(1, 0); ST_B(15);
    BAR; WLG0; PRIO1; SMMA(1); PRIO0;
    WVM0;  // drain: tile 15 complete
    BAR;
    SLOADA(0, 1); SLOADB;
    BAR; WLG0; PRIO1; SMMA(0); PRIO0; BAR;
    SLOADA(1, 1);
    BAR; WLG0; PRIO1; SMMA(1); PRIO0; BAR;
  }

  // Epilogue: exp/mask, row sums (over s) -> atomicAdd, stage [t][s] 128x256
  // (stride 264) in LDS (67.6KB <= 80KB), store to packed triangular strip.
  const int moff = (rt & 1) * 128;  // diag shift: mask if s_loc > t_loc + moff
  float sj[2] = {0.f, 0.f};
#pragma unroll
  for (int qm = 0; qm < 2; ++qm)
#pragma unroll
    for (int i_ = 0; i_ < 4; ++i_) {
      const int s0 = qm * 128 + wr * 64 + i_ * 16 + quad * 4;
#pragma unroll
      for (int j_ = 0; j_ < 2; ++j_) {
        const int t = wc * 32 + j_ * 16 + l15;
        ushort4 o;
        float e[4];
#pragma unroll
        for (int r = 0; r < 4; ++r) {
          float v = __expf(acc[qm][i_][j_][r] * 0.03125f);
          if (maskT && (s0 + r) > (t + moff)) v = 0.f;
          e[r] = v;
          sj[j_] += v;
        }
        o.x = f32_to_bf16(e[0]);
        o.y = f32_to_bf16(e[1]);
        o.z = f32_to_bf16(e[2]);
        o.w = f32_to_bf16(e[3]);
        *(ushort4*)(lds + t * 264 + s0) = o;
      }
    }
#pragma unroll
  for (int j_ = 0; j_ < 2; ++j_) {
    float v = sj[j_];
    v += __shfl_xor(v, 16);
    v += __shfl_xor(v, 32);
    if (quad == 0)
      atomicAdd(&sums[(size_t)b * 2048 + rt * 128 + wc * 32 + j_ * 16 + l15], v);
  }
  __syncthreads();
  const int ld = (rt + 1) * 128;
  const int nc = ld - ct * 256;  // 256 normally; 128 on even-rt last tile
  u16* Out = Spk + (size_t)b * S_BATCH + (size_t)(rt * (rt + 1) / 2) * 16384 +
             ct * 256;
  if (nc >= 256) {
#pragma unroll
    for (int p = 0; p < 8; ++p) {
      const int row = p * 16 + (tid >> 5);
      const int c0 = (tid & 31) * 8;
      const uint4 v = *(const uint4*)(lds + row * 264 + c0);
      *(uint4*)(Out + (size_t)row * ld + c0) = v;
    }
  } else {
#pragma unroll
    for (int p = 0; p < 4; ++p) {
      const int row = p * 32 + (tid >> 4);
      const int c0 = (tid & 15) * 8;
      const uint4 v = *(const uint4*)(lds + row * 264 + c0);
      *(uint4*)(Out + (size_t)row * ld + c0) = v;
    }
  }
#undef ST_A0
#undef ST_A1
#undef ST_B
#undef SLOADA
#undef SLOADB
#undef SMMA
#undef BAR
#undef WLG0
#undef PRIO1
#undef PRIO0
#undef WVM2
#undef WVM0
}

// ---------------------------------------------------------------------------
// PV — 256(c) x 128(t) tile, 8 waves, same 80KB single-B schedule as score
// -> 2 blocks/CU, single co-resident round (512 blocks).  CU pairing: first
// 256 blocks rt=15-(rr>>5), second 256 rt=(rr>>5): each CU totals (15-k)+k+2
// = 17 K-tile-pairs.
// out[b][t][c] = (1/sums[b][t]) * sum_s S[b][t][s] * Vt[b][c][s].
// ---------------------------------------------------------------------------
__global__ __launch_bounds__(512, 4) void pv_kernel(const u16* __restrict__ Spk,
                                                    const u16* __restrict__ Vt,
                                                    const float* __restrict__ sums,
                                                    float* __restrict__ Out) {
  __shared__ __align__(16) u16 lds[40960];  // 80 KB

  const int id = blockIdx.x;       // 0..511
  const int hf = id >> 8;
  const int rr_ = id & 255;
  const int rt = hf ? (rr_ >> 5) : 15 - (rr_ >> 5);  // co-resident pairing
  const int ct = (rr_ >> 3) & 3;
  const int b = rr_ & 7;

  const int ldb = (rt + 1) * 128;
  const int nk2 = rt + 1;          // K-tile pairs; kIters = 2*nk2

  const int tid = threadIdx.x;
  const int srow = tid >> 3;
  const int sgrp = ((tid & 7) - srow) & 7;
  const u16* A = Vt + ((size_t)b * 1024 + ct * 256) * 2048;   // 256 c-rows
  const u16* B = Spk + (size_t)b * S_BATCH +
                 (size_t)(rt * (rt + 1) / 2) * 16384;         // 128 t-rows
  const u16* Ag = A + (size_t)srow * 2048 + sgrp * 8;
  const u16* Bg = B + (size_t)srow * ldb + sgrp * 8;
  char* ldsDst = (char*)lds + tid * 16;

#define ST_A0(kt) do { const u16* s_ = Ag + (kt) * 64;            char* d_ = ldsDst + (((kt) & 1) * 16384);         gl2lds16(s_, d_); gl2lds16(s_ + 131072, d_ + 8192); } while (0)
#define ST_A1(kt) do { const u16* s_ = Ag + 262144 + (kt) * 64;   char* d_ = ldsDst + 32768 + (((kt) & 1) * 16384); gl2lds16(s_, d_); gl2lds16(s_ + 131072, d_ + 8192); } while (0)
#define ST_B(kt)  do { const u16* s_ = Bg + (kt) * 64;            char* d_ = ldsDst + 65536;                        gl2lds16(s_, d_); gl2lds16(s_ + (size_t)64 * ldb, d_ + 8192); } while (0)

  // Prologue: K-tile 0 complete + A0 of K-tile 1.
  ST_A0(0); ST_B(0); ST_A1(0); ST_A0(1);

  const int lane = tid & 63, wid = tid >> 6;
  const int wr = wid >> 2, wc = wid & 3;
  const int l15 = lane & 15, quad = lane >> 4;

  int aoff[4][2], boff[2][2];
#pragma unroll
  for (int i_ = 0; i_ < 4; ++i_) {
    const int arow = wr * 64 + i_ * 16 + l15;
#pragma unroll
    for (int k_ = 0; k_ < 2; ++k_)
      aoff[i_][k_] = arow * 64 + ((k_ * 4 + quad + arow) & 7) * 8;
  }
#pragma unroll
  for (int j_ = 0; j_ < 2; ++j_) {
    const int brow = wc * 32 + j_ * 16 + l15;
#pragma unroll
    for (int k_ = 0; k_ < 2; ++k_)
      boff[j_][k_] = brow * 64 + ((k_ * 4 + quad + brow) & 7) * 8;
  }

  f32x4 acc[2][4][2];
#pragma unroll
  for (int q_ = 0; q_ < 2; ++q_)
#pragma unroll
    for (int i_ = 0; i_ < 4; ++i_)
#pragma unroll
      for (int j_ = 0; j_ < 2; ++j_)
        acc[q_][i_][j_] = (f32x4){0.f, 0.f, 0.f, 0.f};

  bf16x8 af[4][2], bfr[2][2];

#define SLOADA(qm, buf) do { const u16* p_ = lds + (qm) * 16384 + (buf) * 8192; \
  _Pragma("unroll") for (int i_ = 0; i_ < 4; ++i_) \
  _Pragma("unroll") for (int k_ = 0; k_ < 2; ++k_) \
    af[i_][k_] = *(const bf16x8*)(p_ + aoff[i_][k_]); } while (0)
#define SLOADB do { const u16* p_ = lds + 32768; \
  _Pragma("unroll") for (int j_ = 0; j_ < 2; ++j_) \
  _Pragma("unroll") for (int k_ = 0; k_ < 2; ++k_) \
    bfr[j_][k_] = *(const bf16x8*)(p_ + boff[j_][k_]); } while (0)
#define SMMA(qm) do { \
  _Pragma("unroll") for (int i_ = 0; i_ < 4; ++i_) \
  _Pragma("unroll") for (int j_ = 0; j_ < 2; ++j_) \
  _Pragma("unroll") for (int k_ = 0; k_ < 2; ++k_) \
    acc[qm][i_][j_] = __builtin_amdgcn_mfma_f32_16x16x32_bf16( \
        af[i_][k_], bfr[j_][k_], acc[qm][i_][j_], 0, 0, 0); } while (0)

#define BAR __builtin_amdgcn_s_barrier()
#define WLG0 asm volatile("s_waitcnt lgkmcnt(0)")
#define PRIO1 __builtin_amdgcn_s_setprio(1)
#define PRIO0 __builtin_amdgcn_s_setprio(0)
#define WVM2 asm volatile("s_waitcnt vmcnt(2)" ::: "memory")
#define WVM0 asm volatile("s_waitcnt vmcnt(0)" ::: "memory")

  WVM2;  // K-tile 0 landed (A0(1) may be in flight)
  BAR;

#pragma unroll 1
  for (int it = 0; it < nk2 - 1; ++it) {
    const int j0 = 2 * it;
    // Q1(j0) buf0
    SLOADA(0, 0); SLOADB; ST_A1(j0 + 1);
    BAR; WLG0; PRIO1; SMMA(0); PRIO0; BAR;
    // Q2(j0)
    SLOADA(1, 0); ST_B(j0 + 1); ST_A0(j0 + 2);
    BAR; WLG0; PRIO1; SMMA(1); PRIO0;
    WVM2;
    BAR;
    // Q1(j0+1) buf1
    SLOADA(0, 1); SLOADB; ST_A1(j0 + 2);
    BAR; WLG0; PRIO1; SMMA(0); PRIO0; BAR;
    // Q2(j0+1)
    SLOADA(1, 1); ST_B(j0 + 2); ST_A0(j0 + 3);
    BAR; WLG0; PRIO1; SMMA(1); PRIO0;
    WVM2;
    BAR;
  }
  {  // tail: K-tiles 2*nk2-2 (buf0), 2*nk2-1 (buf1)
    SLOADA(0, 0); SLOADB; ST_A1(2 * nk2 - 1);
    BAR; WLG0; PRIO1; SMMA(0); PRIO0; BAR;
    SLOADA(1, 0); ST_B(2 * nk2 - 1);
    BAR; WLG0; PRIO1; SMMA(1); PRIO0;
    WVM0;  // drain: last K-tile complete
    BAR;
    SLOADA(0, 1); SLOADB;
    BAR; WLG0; PRIO1; SMMA(0); PRIO0; BAR;
    SLOADA(1, 1);
    BAR; WLG0; PRIO1; SMMA(1); PRIO0; BAR;
  }

  // Epilogue: scale by 1/sums, stage fp32 [t 128][c 132] per c-half, store.
  float* ftile = (float*)lds;   // 128 x 132 fp32 = 67584 B (fits 80KB)
  const float* sumsb = sums + (size_t)b * 2048 + rt * 128;
  float* Ob = Out + (size_t)b * 2048 * 1024 + (size_t)(rt * 128) * 1024 +
              ct * 256;
  float iv[2];
#pragma unroll
  for (int j_ = 0; j_ < 2; ++j_)
    iv[j_] = 1.0f / sumsb[wc * 32 + j_ * 16 + l15];
#pragma unroll
  for (int qm = 0; qm < 2; ++qm) {
    if (qm) __syncthreads();
#pragma unroll
    for (int i_ = 0; i_ < 4; ++i_) {
      const int c0 = wr * 64 + i_ * 16 + quad * 4;
#pragma unroll
      for (int j_ = 0; j_ < 2; ++j_) {
        const int t = wc * 32 + j_ * 16 + l15;
        float4 v;
        v.x = acc[qm][i_][j_][0] * iv[j_];
        v.y = acc[qm][i_][j_][1] * iv[j_];
        v.z = acc[qm][i_][j_][2] * iv[j_];
        v.w = acc[qm][i_][j_][3] * iv[j_];
        *(float4*)(ftile + t * 132 + c0) = v;
      }
    }
    __syncthreads();
#pragma unroll
    for (int p = 0; p < 8; ++p) {
      const int row = p * 16 + (tid >> 5);
      const int c0f = (tid & 31) * 4;
      const float4 v = *(const float4*)(ftile + row * 132 + c0f);
      *(float4*)(Ob + (size_t)row * 1024 + qm * 128 + c0f) = v;
    }
  }
#undef ST_A0
#undef ST_A1
#undef ST_B
#undef SLOADA
#undef SLOADB
#undef SMMA
#undef BAR
#undef WLG0
#undef PRIO1
#undef PRIO0
#undef WVM2
#undef WVM0
}

// ---------------------------------------------------------------------------
extern "C" void kernel_launch(void* const* d_in, const int* in_sizes, int n_in,
                              void* d_out, int out_size, void* d_ws,
                              size_t ws_size, hipStream_t stream) {
  const float* x = (const float*)d_in[0];
  const float* wq = (const float*)d_in[1];
  const float* bq = (const float*)d_in[2];
  const float* wk = (const float*)d_in[3];
  const float* bk = (const float*)d_in[4];
  const float* wv = (const float*)d_in[5];
  const float* bv = (const float*)d_in[6];
  float* out = (float*)d_out;
  char* ws = (char*)d_ws;

  // Workspace layout (<=160 MB):
  //   [0,32M)      Qb bf16 [16384][1024]
  //   [32,64M)     Kb bf16 [16384][1024]
  //   [64,96M)     Vt bf16 [8][1024][2048]
  //   [96,130.1M)  Spk bf16 packed triangular [8][136*16384]
  //   [132,132.07M) sums fp32 [16384]
  //   [134,140M)   wb bf16 [3][1024][1024]
  //   xb (32MB @96M) aliases Spk: dead after qkv pass.
  u16* Qb = (u16*)(ws);
  u16* Kb = (u16*)(ws + ((size_t)32 << 20));
  u16* Vt = (u16*)(ws + ((size_t)64 << 20));
  u16* Spk = (u16*)(ws + ((size_t)96 << 20));
  u16* xb = (u16*)(ws + ((size_t)96 << 20));   // alias: dies before Spk written
  float* sums = (float*)(ws + ((size_t)132 << 20));
  u16* wb = (u16*)(ws + ((size_t)134 << 20));

  // pass 0: casts + sums zero-init
  cast_f32_to_bf16_kernel<<<16384, 256, 0, stream>>>(x, xb, 16777216 / 4);
  cast_w_kernel<<<dim3(512, 4), 256, 0, stream>>>(wq, wk, wv, wb, sums);

  // pass 1: fused Q,K,V projections (V transposed), 256^2 8-phase (round-3)
  qkv_kernel<<<768, 512, 0, stream>>>(xb, wb, bq, bk, bv, Qb, Kb, Vt);

  // pass 2: causal exp-scores, 80KB LDS -> 2 blocks/CU
  score_kernel<<<576, 512, 0, stream>>>(Kb, Qb, Spk, sums);

  // pass 3: P @ V, 80KB LDS -> 2 blocks/CU, one balanced round
  pv_kernel<<<512, 512, 0, stream>>>(Spk, Vt, sums, out);
}

// Round 6
// 324.935 us; speedup vs baseline: 1.1121x; 1.1121x over previous
//
#include <hip/hip_runtime.h>
#include <stdint.h>

typedef unsigned short u16;
typedef __attribute__((ext_vector_type(8))) __bf16 bf16x8;
typedef __attribute__((ext_vector_type(4))) float f32x4;

#define DEVI __device__ __forceinline__

DEVI u16 f32_to_bf16(float f) {
  uint32_t u = __builtin_bit_cast(uint32_t, f);
  u += 0x7FFFu + ((u >> 16) & 1u);   // RNE; inputs are never NaN here
  return (u16)(u >> 16);
}

DEVI void gl2lds16(const void* g, void* l) {
  __builtin_amdgcn_global_load_lds(
      (const __attribute__((address_space(1))) void*)g,
      (__attribute__((address_space(3))) void*)l, 16, 0, 0);
}

// S is packed triangular: per batch, strip rt (128 rows) has row stride
// (rt+1)*128 and begins at tri(rt)*16384 u16.  Per-batch size 136*16384 u16.
#define S_BATCH 2228224  // u16 elements per batch = 136*16384

// ---------------------------------------------------------------------------
// Fused input casts: x (4M float4), weights (3x256K float4), sums zero-init.
// One dispatch, grid-stride (G11: 2048 blocks), memory-bound.
// ---------------------------------------------------------------------------
__global__ void cast_all_kernel(const float* __restrict__ x,
                                const float* __restrict__ wq,
                                const float* __restrict__ wk,
                                const float* __restrict__ wv,
                                u16* __restrict__ xb, u16* __restrict__ wb,
                                float* __restrict__ sums) {
  const int i0 = blockIdx.x * blockDim.x + threadIdx.x;
  const int stride = gridDim.x * blockDim.x;   // 524288
  for (int j = i0; j < 4194304; j += stride) {  // x -> xb
    const float4 v = ((const float4*)x)[j];
    ushort4 o;
    o.x = f32_to_bf16(v.x);
    o.y = f32_to_bf16(v.y);
    o.z = f32_to_bf16(v.z);
    o.w = f32_to_bf16(v.w);
    ((ushort4*)xb)[j] = o;
  }
  for (int j = i0; j < 786432; j += stride) {   // wq|wk|wv -> wb
    const int z = j >> 18;
    const int r = j & 262143;
    const float* src = (z == 0) ? wq : (z == 1) ? wk : wv;
    const float4 v = ((const float4*)src)[r];
    ushort4 o;
    o.x = f32_to_bf16(v.x);
    o.y = f32_to_bf16(v.y);
    o.z = f32_to_bf16(v.z);
    o.w = f32_to_bf16(v.w);
    ((ushort4*)(wb + (size_t)z * 1048576))[r] = o;
  }
  if (i0 < 4096) ((float4*)sums)[i0] = (float4){0.f, 0.f, 0.f, 0.f};
}

// ---------------------------------------------------------------------------
// Fused Q/K/V projection — 256x256-tile, 8-wave, 8-phase schedule (T3+T4+T5).
// ROUND-3 VERSION, re-measured r5: 105.9 us / MfmaUtil 40.5%.  Do not touch:
// read-ahead variant (r2) and persistent variant (r4) both regressed.
// ---------------------------------------------------------------------------
__global__ __launch_bounds__(512, 2) void qkv_kernel(
    const u16* __restrict__ xb, const u16* __restrict__ wb,
    const float* __restrict__ bq, const float* __restrict__ bk,
    const float* __restrict__ bv, u16* __restrict__ Qb, u16* __restrict__ Kb,
    u16* __restrict__ Vt) {
  __shared__ __align__(16) u16 lds[65536];  // 128 KB

  const int id = blockIdx.x;                 // 0..767
  const int wg = (id & 7) * 96 + (id >> 3);  // bijective XCD swizzle (768%8==0)
  const int g = wg >> 3, u = wg & 7;         // groups of 8 tiles: 4c x 2t (~3MB L2)
  const int z = g >> 5;                      // 0..2
  const int tp = g & 31;                     // t-pair
  const int tmt = tp * 2 + (u >> 2);         // t-tile 0..63
  const int tct = u & 3;                     // c-tile 0..3

  // Q/K: A=W (m=c, reg-quad packs c); V: A=x (m=t, reg-quad packs t).
  int m0, n0;
  const u16* Aptr;
  const u16* Bptr;
  if (z < 2) {
    m0 = tct * 256;
    n0 = tmt * 256;
    Aptr = wb + (size_t)z * 1048576 + (size_t)m0 * 1024;
    Bptr = xb + (size_t)n0 * 1024;
  } else {
    m0 = tmt * 256;
    n0 = tct * 256;
    Aptr = xb + (size_t)m0 * 1024;
    Bptr = wb + (size_t)2 * 1048576 + (size_t)n0 * 1024;
  }

  const int tid = threadIdx.x;
  const int srow = tid >> 3;                 // staged row 0..63 (+64 2nd load)
  const int sgrp = ((tid & 7) - srow) & 7;   // rotated source column-group
  const u16* Ag = Aptr + (size_t)srow * 1024 + sgrp * 8;
  const u16* Bg = Bptr + (size_t)srow * 1024 + sgrp * 8;
  char* ldsDst = (char*)lds + tid * 16;

  // Half-tile stagers: 2 x gl_lds x 16B per thread = 128 rows x 64 cols bf16.
#define ST_A0(kt) do { const u16* s_ = Ag + (kt) * 64;           char* d_ = ldsDst + (((kt) & 1) * 65536);         gl2lds16(s_, d_); gl2lds16(s_ + 65536, d_ + 8192); } while (0)
#define ST_A1(kt) do { const u16* s_ = Ag + 131072 + (kt) * 64;  char* d_ = ldsDst + (((kt) & 1) * 65536) + 16384; gl2lds16(s_, d_); gl2lds16(s_ + 65536, d_ + 8192); } while (0)
#define ST_B0(kt) do { const u16* s_ = Bg + (kt) * 64;           char* d_ = ldsDst + (((kt) & 1) * 65536) + 32768; gl2lds16(s_, d_); gl2lds16(s_ + 65536, d_ + 8192); } while (0)
#define ST_B1(kt) do { const u16* s_ = Bg + 131072 + (kt) * 64;  char* d_ = ldsDst + (((kt) & 1) * 65536) + 49152; gl2lds16(s_, d_); gl2lds16(s_ + 65536, d_ + 8192); } while (0)

  // Prologue: K-tile 0 complete + A0/B0/B1 of K-tile 1 (7 half-tiles).
  ST_A0(0); ST_B0(0); ST_B1(0); ST_A1(0);
  ST_A0(1); ST_B0(1); ST_B1(1);

  const int lane = tid & 63, wid = tid >> 6;
  const int wr = wid >> 2, wc = wid & 3;
  const int l15 = lane & 15, quad = lane >> 4;

  int aoff[4][2], boff[2][2];
#pragma unroll
  for (int i_ = 0; i_ < 4; ++i_) {
    const int arow = wr * 64 + i_ * 16 + l15;
#pragma unroll
    for (int k_ = 0; k_ < 2; ++k_)
      aoff[i_][k_] = arow * 64 + ((k_ * 4 + quad + arow) & 7) * 8;
  }
#pragma unroll
  for (int j_ = 0; j_ < 2; ++j_) {
    const int brow = wc * 32 + j_ * 16 + l15;
#pragma unroll
    for (int k_ = 0; k_ < 2; ++k_)
      boff[j_][k_] = brow * 64 + ((k_ * 4 + quad + brow) & 7) * 8;
  }

  f32x4 acc[2][2][4][2];
#pragma unroll
  for (int a_ = 0; a_ < 2; ++a_)
#pragma unroll
    for (int b_ = 0; b_ < 2; ++b_)
#pragma unroll
      for (int i_ = 0; i_ < 4; ++i_)
#pragma unroll
        for (int j_ = 0; j_ < 2; ++j_)
          acc[a_][b_][i_][j_] = (f32x4){0.f, 0.f, 0.f, 0.f};

  bf16x8 af[4][2], bfr[2][2][2];

#define LOADA(qm, buf) do { const u16* p_ = lds + (buf) * 32768 + (qm) * 8192; \
  _Pragma("unroll") for (int i_ = 0; i_ < 4; ++i_) \
  _Pragma("unroll") for (int k_ = 0; k_ < 2; ++k_) \
    af[i_][k_] = *(const bf16x8*)(p_ + aoff[i_][k_]); } while (0)
#define LOADB(qn, buf) do { const u16* p_ = lds + (buf) * 32768 + 16384 + (qn) * 8192; \
  _Pragma("unroll") for (int j_ = 0; j_ < 2; ++j_) \
  _Pragma("unroll") for (int k_ = 0; k_ < 2; ++k_) \
    bfr[qn][j_][k_] = *(const bf16x8*)(p_ + boff[j_][k_]); } while (0)
#define MMA(qm, qn) do { \
  _Pragma("unroll") for (int i_ = 0; i_ < 4; ++i_) \
  _Pragma("unroll") for (int j_ = 0; j_ < 2; ++j_) \
  _Pragma("unroll") for (int k_ = 0; k_ < 2; ++k_) \
    acc[qm][qn][i_][j_] = __builtin_amdgcn_mfma_f32_16x16x32_bf16( \
        af[i_][k_], bfr[qn][j_][k_], acc[qm][qn][i_][j_], 0, 0, 0); } while (0)

#define BAR __builtin_amdgcn_s_barrier()
#define WLG0 asm volatile("s_waitcnt lgkmcnt(0)")
#define WLG8 asm volatile("s_waitcnt lgkmcnt(8)")
#define PRIO1 __builtin_amdgcn_s_setprio(1)
#define PRIO0 __builtin_amdgcn_s_setprio(0)
#define WVM6 asm volatile("s_waitcnt vmcnt(6)" ::: "memory")
#define WVM0 asm volatile("s_waitcnt vmcnt(0)" ::: "memory")

  WVM6;  // K-tile 0 landed
  BAR;

#pragma unroll 1
  for (int it = 0; it < 7; ++it) {
    const int j0 = 2 * it;
    // P1 (0,0) buf0
    LOADA(0, 0); LOADB(0, 0); ST_A1(j0 + 1); WLG8;
    BAR; WLG0; PRIO1; MMA(0, 0); PRIO0; BAR;
    // P2 (0,1)
    LOADB(1, 0); ST_A0(j0 + 2);
    BAR; WLG0; PRIO1; MMA(0, 1); PRIO0; BAR;
    // P3 (1,1)
    LOADA(1, 0); ST_B0(j0 + 2);
    BAR; WLG0; PRIO1; MMA(1, 1); PRIO0; BAR;
    // P4 (1,0)
    ST_B1(j0 + 2);
    BAR; PRIO1; MMA(1, 0); PRIO0;
    WVM6;  // K-tile j0+1 landed
    BAR;
    // P5 (0,0) buf1
    LOADA(0, 1); LOADB(0, 1); ST_A1(j0 + 2); WLG8;
    BAR; WLG0; PRIO1; MMA(0, 0); PRIO0; BAR;
    // P6 (0,1)
    LOADB(1, 1); ST_A0(j0 + 3);
    BAR; WLG0; PRIO1; MMA(0, 1); PRIO0; BAR;
    // P7 (1,1)
    LOADA(1, 1); ST_B0(j0 + 3);
    BAR; WLG0; PRIO1; MMA(1, 1); PRIO0; BAR;
    // P8 (1,0)
    ST_B1(j0 + 3);
    BAR; PRIO1; MMA(1, 0); PRIO0;
    WVM6;  // K-tile j0+2 landed
    BAR;
  }
  {  // it = 7: K-tiles 14 (buf0) / 15 (buf1); only A1(15) left to stage
    LOADA(0, 0); LOADB(0, 0); ST_A1(15); WLG8;
    BAR; WLG0; PRIO1; MMA(0, 0); PRIO0; BAR;
    LOADB(1, 0);
    BAR; WLG0; PRIO1; MMA(0, 1); PRIO0; BAR;
    LOADA(1, 0);
    BAR; WLG0; PRIO1; MMA(1, 1); PRIO0; BAR;
    BAR; PRIO1; MMA(1, 0); PRIO0;
    WVM0;  // drain: K-tile 15 landed
    BAR;
    LOADA(0, 1); LOADB(0, 1); WLG8;
    BAR; WLG0; PRIO1; MMA(0, 0); PRIO0; BAR;
    LOADB(1, 1);
    BAR; WLG0; PRIO1; MMA(0, 1); PRIO0; BAR;
    LOADA(1, 1);
    BAR; WLG0; PRIO1; MMA(1, 1); PRIO0; BAR;
    PRIO1; MMA(1, 0); PRIO0;
    BAR;  // mainloop done; LDS reusable
  }

  // Epilogue: per N-half th, stage [128 n-rows][256 m-cols] (+8 pad) in LDS,
  // then full-line 16B/lane global stores.
  if (z < 2) {
    const float* bias = (z == 0) ? bq : bk;
    u16* Out = (z == 0) ? Qb : Kb;
#pragma unroll
    for (int th = 0; th < 2; ++th) {
      if (th) __syncthreads();
#pragma unroll
      for (int qm = 0; qm < 2; ++qm)
#pragma unroll
        for (int i_ = 0; i_ < 4; ++i_) {
          const int c = qm * 128 + wr * 64 + i_ * 16 + quad * 4;
          const float4 b4 = *(const float4*)(bias + m0 + c);
#pragma unroll
          for (int j_ = 0; j_ < 2; ++j_) {
            const int row = wc * 32 + j_ * 16 + l15;
            ushort4 o;
            o.x = f32_to_bf16(acc[qm][th][i_][j_][0] + b4.x);
            o.y = f32_to_bf16(acc[qm][th][i_][j_][1] + b4.y);
            o.z = f32_to_bf16(acc[qm][th][i_][j_][2] + b4.z);
            o.w = f32_to_bf16(acc[qm][th][i_][j_][3] + b4.w);
            *(ushort4*)(lds + row * 264 + c) = o;   // [t][c]
          }
        }
      __syncthreads();
#pragma unroll
      for (int p = 0; p < 8; ++p) {
        const int row = p * 16 + (tid >> 5);
        const int c0 = (tid & 31) * 8;
        const uint4 v = *(const uint4*)(lds + row * 264 + c0);
        *(uint4*)(Out + (size_t)(n0 + th * 128 + row) * 1024 + m0 + c0) = v;
      }
    }
  } else {
    const int b = m0 >> 11;
    const int t0b = m0 & 2047;
    u16* Out = Vt + (size_t)b * 2097152;
#pragma unroll
    for (int th = 0; th < 2; ++th) {
      if (th) __syncthreads();
#pragma unroll
      for (int j_ = 0; j_ < 2; ++j_) {
        const int row = wc * 32 + j_ * 16 + l15;      // c within half
        const float bb = bv[n0 + th * 128 + row];
#pragma unroll
        for (int qm = 0; qm < 2; ++qm)
#pragma unroll
          for (int i_ = 0; i_ < 4; ++i_) {
            const int c = qm * 128 + wr * 64 + i_ * 16 + quad * 4;  // t
            ushort4 o;
            o.x = f32_to_bf16(acc[qm][th][i_][j_][0] + bb);
            o.y = f32_to_bf16(acc[qm][th][i_][j_][1] + bb);
            o.z = f32_to_bf16(acc[qm][th][i_][j_][2] + bb);
            o.w = f32_to_bf16(acc[qm][th][i_][j_][3] + bb);
            *(ushort4*)(lds + row * 264 + c) = o;     // [c][t]
          }
      }
      __syncthreads();
#pragma unroll
      for (int p = 0; p < 8; ++p) {
        const int row = p * 16 + (tid >> 5);
        const int c0 = (tid & 31) * 8;
        const uint4 v = *(const uint4*)(lds + row * 264 + c0);
        *(uint4*)(Out + (size_t)(n0 + th * 128 + row) * 2048 + t0b + c0) = v;
      }
    }
  }
#undef ST_A0
#undef ST_A1
#undef ST_B0
#undef ST_B1
#undef LOADA
#undef LOADB
#undef MMA
#undef BAR
#undef WLG0
#undef WLG8
#undef PRIO1
#undef PRIO0
#undef WVM6
#undef WVM0
}

// ---------------------------------------------------------------------------
// Scores — 256(s) x 128(t) tile, 8 waves, 2 phases/K-tile, phase-head loads.
// 96KB LDS VERSION (r2-r4, known good; 80KB single-B variant regressed r5).
// S[b][t][s] = exp((K.Q)/32), causal-masked, packed triangular.
// Fragment: s = qm*128 + wr*64 + i*16 + quad*4 + r ; t = wc*32 + j*16 + l15.
// LDS 96KB: 2 bufs x {A0,A1,B} x 16KB (row stride 64 u16, rotated groups).
// Grid 576 = 8 batches (one per XCD) x 72 tiles; all tiles equal cost.
// ---------------------------------------------------------------------------
__global__ __launch_bounds__(512, 2) void score_kernel(const u16* __restrict__ Kb,
                                                       const u16* __restrict__ Qb,
                                                       u16* __restrict__ Spk,
                                                       float* __restrict__ sums) {
  __shared__ __align__(16) u16 lds[49152];  // 96 KB

  const int id = blockIdx.x;   // 0..575
  const int b = id & 7;        // batch per XCD: K/Q tiles stay in XCD L2
  const int l = id >> 3;       // 0..71
  int k = (int)((sqrtf(4.f * l + 1.f) - 1.f) * 0.5f);
  if (k * (k + 1) > l) --k;
  if ((k + 1) * (k + 2) <= l) ++k;
  const int off = l - k * (k + 1);
  const int hi = (off >= (k + 1));
  const int rt = 2 * k + hi;           // t-strip 0..15 (128 rows)
  const int ct = off - (hi ? (k + 1) : 0);  // s-tile 0..k (256 cols)
  const bool maskT = (ct == k);        // only the last s-tile crosses diag

  const int tid = threadIdx.x;
  const int srow = tid >> 3;
  const int sgrp = ((tid & 7) - srow) & 7;
  const u16* A = Qb + ((size_t)b * 2048 + ct * 256) * 1024;  // 256 s-rows
  const u16* B = Kb + ((size_t)b * 2048 + rt * 128) * 1024;  // 128 t-rows
  const u16* Ag = A + (size_t)srow * 1024 + sgrp * 8;
  const u16* Bg = B + (size_t)srow * 1024 + sgrp * 8;
  char* ldsDst = (char*)lds + tid * 16;

#define ST_A0(kt) do { const u16* s_ = Ag + (kt) * 64;           char* d_ = ldsDst + (((kt) & 1) * 49152);         gl2lds16(s_, d_); gl2lds16(s_ + 65536, d_ + 8192); } while (0)
#define ST_A1(kt) do { const u16* s_ = Ag + 131072 + (kt) * 64;  char* d_ = ldsDst + (((kt) & 1) * 49152) + 16384; gl2lds16(s_, d_); gl2lds16(s_ + 65536, d_ + 8192); } while (0)
#define ST_B(kt)  do { const u16* s_ = Bg + (kt) * 64;           char* d_ = ldsDst + (((kt) & 1) * 49152) + 32768; gl2lds16(s_, d_); gl2lds16(s_ + 65536, d_ + 8192); } while (0)

  // Prologue: K-tile 0 complete + A0/B of K-tile 1 (A1(1) staged at Q1).
  ST_A0(0); ST_B(0); ST_A1(0);
  ST_A0(1); ST_B(1);

  const int lane = tid & 63, wid = tid >> 6;
  const int wr = wid >> 2, wc = wid & 3;
  const int l15 = lane & 15, quad = lane >> 4;

  int aoff[4][2], boff[2][2];
#pragma unroll
  for (int i_ = 0; i_ < 4; ++i_) {
    const int arow = wr * 64 + i_ * 16 + l15;
#pragma unroll
    for (int k_ = 0; k_ < 2; ++k_)
      aoff[i_][k_] = arow * 64 + ((k_ * 4 + quad + arow) & 7) * 8;
  }
#pragma unroll
  for (int j_ = 0; j_ < 2; ++j_) {
    const int brow = wc * 32 + j_ * 16 + l15;
#pragma unroll
    for (int k_ = 0; k_ < 2; ++k_)
      boff[j_][k_] = brow * 64 + ((k_ * 4 + quad + brow) & 7) * 8;
  }

  f32x4 acc[2][4][2];
#pragma unroll
  for (int q_ = 0; q_ < 2; ++q_)
#pragma unroll
    for (int i_ = 0; i_ < 4; ++i_)
#pragma unroll
      for (int j_ = 0; j_ < 2; ++j_)
        acc[q_][i_][j_] = (f32x4){0.f, 0.f, 0.f, 0.f};

  bf16x8 af[4][2], bfr[2][2];

#define SLOADA(qm, buf) do { const u16* p_ = lds + (buf) * 24576 + (qm) * 8192; \
  _Pragma("unroll") for (int i_ = 0; i_ < 4; ++i_) \
  _Pragma("unroll") for (int k_ = 0; k_ < 2; ++k_) \
    af[i_][k_] = *(const bf16x8*)(p_ + aoff[i_][k_]); } while (0)
#define SLOADB(buf) do { const u16* p_ = lds + (buf) * 24576 + 16384; \
  _Pragma("unroll") for (int j_ = 0; j_ < 2; ++j_) \
  _Pragma("unroll") for (int k_ = 0; k_ < 2; ++k_) \
    bfr[j_][k_] = *(const bf16x8*)(p_ + boff[j_][k_]); } while (0)
#define SMMA(qm) do { \
  _Pragma("unroll") for (int i_ = 0; i_ < 4; ++i_) \
  _Pragma("unroll") for (int j_ = 0; j_ < 2; ++j_) \
  _Pragma("unroll") for (int k_ = 0; k_ < 2; ++k_) \
    acc[qm][i_][j_] = __builtin_amdgcn_mfma_f32_16x16x32_bf16( \
        af[i_][k_], bfr[j_][k_], acc[qm][i_][j_], 0, 0, 0); } while (0)

#define BAR __builtin_amdgcn_s_barrier()
#define WLG0 asm volatile("s_waitcnt lgkmcnt(0)")
#define PRIO1 __builtin_amdgcn_s_setprio(1)
#define PRIO0 __builtin_amdgcn_s_setprio(0)
#define WVM4 asm volatile("s_waitcnt vmcnt(4)" ::: "memory")
#define WVM0 asm volatile("s_waitcnt vmcnt(0)" ::: "memory")

  WVM4;  // K-tile 0 (3 STs) landed
  BAR;

#pragma unroll 1
  for (int it = 0; it < 7; ++it) {
    const int j0 = 2 * it;
    // Q1 (K-tile j0, qm=0)
    SLOADA(0, 0); SLOADB(0); ST_A1(j0 + 1);
    BAR; WLG0; PRIO1; SMMA(0); PRIO0; BAR;
    // Q2 (j0, qm=1)
    SLOADA(1, 0); ST_A0(j0 + 2); ST_B(j0 + 2);
    BAR; WLG0; PRIO1; SMMA(1); PRIO0;
    WVM4;  // K-tile j0+1 landed
    BAR;
    // Q3 (j0+1, qm=0)
    SLOADA(0, 1); SLOADB(1); ST_A1(j0 + 2);
    BAR; WLG0; PRIO1; SMMA(0); PRIO0; BAR;
    // Q4 (j0+1, qm=1)
    SLOADA(1, 1); ST_A0(j0 + 3); ST_B(j0 + 3);
    BAR; WLG0; PRIO1; SMMA(1); PRIO0;
    WVM4;  // K-tile j0+2 landed
    BAR;
  }
  {  // tail: K-tiles 14, 15
    SLOADA(0, 0); SLOADB(0); ST_A1(15);
    BAR; WLG0; PRIO1; SMMA(0); PRIO0; BAR;
    SLOADA(1, 0);
    BAR; WLG0; PRIO1; SMMA(1); PRIO0;
    WVM0;  // drain (K-tile 15 complete)
    BAR;
    SLOADA(0, 1); SLOADB(1);
    BAR; WLG0; PRIO1; SMMA(0); PRIO0; BAR;
    SLOADA(1, 1);
    BAR; WLG0; PRIO1; SMMA(1); PRIO0; BAR;
  }

  // Epilogue: exp/mask, row sums (over s) -> atomicAdd, stage [t][s] 128x256
  // (stride 264) in LDS, store to the packed triangular strip.
  const int moff = (rt & 1) * 128;  // diag shift: mask if s_loc > t_loc + moff
  float sj[2] = {0.f, 0.f};
#pragma unroll
  for (int qm = 0; qm < 2; ++qm)
#pragma unroll
    for (int i_ = 0; i_ < 4; ++i_) {
      const int s0 = qm * 128 + wr * 64 + i_ * 16 + quad * 4;
#pragma unroll
      for (int j_ = 0; j_ < 2; ++j_) {
        const int t = wc * 32 + j_ * 16 + l15;
        ushort4 o;
        float e[4];
#pragma unroll
        for (int r = 0; r < 4; ++r) {
          float v = __expf(acc[qm][i_][j_][r] * 0.03125f);
          if (maskT && (s0 + r) > (t + moff)) v = 0.f;
          e[r] = v;
          sj[j_] += v;
        }
        o.x = f32_to_bf16(e[0]);
        o.y = f32_to_bf16(e[1]);
        o.z = f32_to_bf16(e[2]);
        o.w = f32_to_bf16(e[3]);
        *(ushort4*)(lds + t * 264 + s0) = o;
      }
    }
#pragma unroll
  for (int j_ = 0; j_ < 2; ++j_) {
    float v = sj[j_];
    v += __shfl_xor(v, 16);
    v += __shfl_xor(v, 32);
    if (quad == 0)
      atomicAdd(&sums[(size_t)b * 2048 + rt * 128 + wc * 32 + j_ * 16 + l15], v);
  }
  __syncthreads();
  const int ld = (rt + 1) * 128;
  const int nc = ld - ct * 256;  // 256 normally; 128 on even-rt last tile
  u16* Out = Spk + (size_t)b * S_BATCH + (size_t)(rt * (rt + 1) / 2) * 16384 +
             ct * 256;
  if (nc >= 256) {
#pragma unroll
    for (int p = 0; p < 8; ++p) {
      const int row = p * 16 + (tid >> 5);
      const int c0 = (tid & 31) * 8;
      const uint4 v = *(const uint4*)(lds + row * 264 + c0);
      *(uint4*)(Out + (size_t)row * ld + c0) = v;
    }
  } else {
#pragma unroll
    for (int p = 0; p < 4; ++p) {
      const int row = p * 32 + (tid >> 4);
      const int c0 = (tid & 15) * 8;
      const uint4 v = *(const uint4*)(lds + row * 264 + c0);
      *(uint4*)(Out + (size_t)row * ld + c0) = v;
    }
  }
#undef ST_A0
#undef ST_A1
#undef ST_B
#undef SLOADA
#undef SLOADB
#undef SMMA
#undef BAR
#undef WLG0
#undef PRIO1
#undef PRIO0
#undef WVM4
#undef WVM0
}

// ---------------------------------------------------------------------------
// PV — 256(c) x 128(t) tile, 8 waves, 2 phases/K-tile, phase-head loads.
// 96KB LDS VERSION (r4, known good; 80KB single-B variant regressed r5).
// out[b][t][c] = (1/sums[b][t]) * sum_s S[b][t][s] * Vt[b][c][s].
// Grid 512, 1 block/CU, 2 rounds.  First 256 blocks rt 15..8 (heavy), second
// 256 rt 7..0 DESCENDING: earliest-freed CUs take the heaviest queued blocks
// -> every CU totals ~17 K-tile-pairs.
// ---------------------------------------------------------------------------
__global__ __launch_bounds__(512, 2) void pv_kernel(const u16* __restrict__ Spk,
                                                    const u16* __restrict__ Vt,
                                                    const float* __restrict__ sums,
                                                    float* __restrict__ Out) {
  __shared__ __align__(16) u16 lds[49152];  // 96 KB

  const int id = blockIdx.x;       // 0..511
  const int hf = id >> 8;
  const int rr_ = id & 255;
  const int rt = (hf ? 7 : 15) - (rr_ >> 5);   // balanced pairing (17/CU)
  const int ct = (rr_ >> 3) & 3;
  const int b = rr_ & 7;

  const int ldb = (rt + 1) * 128;
  const int nk2 = rt + 1;          // K-tile pairs; kIters = 2*nk2

  const int tid = threadIdx.x;
  const int srow = tid >> 3;
  const int sgrp = ((tid & 7) - srow) & 7;
  const u16* A = Vt + ((size_t)b * 1024 + ct * 256) * 2048;   // 256 c-rows
  const u16* B = Spk + (size_t)b * S_BATCH +
                 (size_t)(rt * (rt + 1) / 2) * 16384;         // 128 t-rows
  const u16* Ag = A + (size_t)srow * 2048 + sgrp * 8;
  const u16* Bg = B + (size_t)srow * ldb + sgrp * 8;
  char* ldsDst = (char*)lds + tid * 16;

#define ST_A0(kt) do { const u16* s_ = Ag + (kt) * 64;            char* d_ = ldsDst + (((kt) & 1) * 49152);         gl2lds16(s_, d_); gl2lds16(s_ + 131072, d_ + 8192); } while (0)
#define ST_A1(kt) do { const u16* s_ = Ag + 262144 + (kt) * 64;   char* d_ = ldsDst + (((kt) & 1) * 49152) + 16384; gl2lds16(s_, d_); gl2lds16(s_ + 131072, d_ + 8192); } while (0)
#define ST_B(kt)  do { const u16* s_ = Bg + (kt) * 64;            char* d_ = ldsDst + (((kt) & 1) * 49152) + 32768; gl2lds16(s_, d_); gl2lds16(s_ + (size_t)64 * ldb, d_ + 8192); } while (0)

  // Prologue: K-tile 0 complete + A0/B of K-tile 1.
  ST_A0(0); ST_B(0); ST_A1(0);
  ST_A0(1); ST_B(1);

  const int lane = tid & 63, wid = tid >> 6;
  const int wr = wid >> 2, wc = wid & 3;
  const int l15 = lane & 15, quad = lane >> 4;

  int aoff[4][2], boff[2][2];
#pragma unroll
  for (int i_ = 0; i_ < 4; ++i_) {
    const int arow = wr * 64 + i_ * 16 + l15;
#pragma unroll
    for (int k_ = 0; k_ < 2; ++k_)
      aoff[i_][k_] = arow * 64 + ((k_ * 4 + quad + arow) & 7) * 8;
  }
#pragma unroll
  for (int j_ = 0; j_ < 2; ++j_) {
    const int brow = wc * 32 + j_ * 16 + l15;
#pragma unroll
    for (int k_ = 0; k_ < 2; ++k_)
      boff[j_][k_] = brow * 64 + ((k_ * 4 + quad + brow) & 7) * 8;
  }

  f32x4 acc[2][4][2];
#pragma unroll
  for (int q_ = 0; q_ < 2; ++q_)
#pragma unroll
    for (int i_ = 0; i_ < 4; ++i_)
#pragma unroll
      for (int j_ = 0; j_ < 2; ++j_)
        acc[q_][i_][j_] = (f32x4){0.f, 0.f, 0.f, 0.f};

  bf16x8 af[4][2], bfr[2][2];

#define SLOADA(qm, buf) do { const u16* p_ = lds + (buf) * 24576 + (qm) * 8192; \
  _Pragma("unroll") for (int i_ = 0; i_ < 4; ++i_) \
  _Pragma("unroll") for (int k_ = 0; k_ < 2; ++k_) \
    af[i_][k_] = *(const bf16x8*)(p_ + aoff[i_][k_]); } while (0)
#define SLOADB(buf) do { const u16* p_ = lds + (buf) * 24576 + 16384; \
  _Pragma("unroll") for (int j_ = 0; j_ < 2; ++j_) \
  _Pragma("unroll") for (int k_ = 0; k_ < 2; ++k_) \
    bfr[j_][k_] = *(const bf16x8*)(p_ + boff[j_][k_]); } while (0)
#define SMMA(qm) do { \
  _Pragma("unroll") for (int i_ = 0; i_ < 4; ++i_) \
  _Pragma("unroll") for (int j_ = 0; j_ < 2; ++j_) \
  _Pragma("unroll") for (int k_ = 0; k_ < 2; ++k_) \
    acc[qm][i_][j_] = __builtin_amdgcn_mfma_f32_16x16x32_bf16( \
        af[i_][k_], bfr[j_][k_], acc[qm][i_][j_], 0, 0, 0); } while (0)

#define BAR __builtin_amdgcn_s_barrier()
#define WLG0 asm volatile("s_waitcnt lgkmcnt(0)")
#define PRIO1 __builtin_amdgcn_s_setprio(1)
#define PRIO0 __builtin_amdgcn_s_setprio(0)
#define WVM4 asm volatile("s_waitcnt vmcnt(4)" ::: "memory")
#define WVM0 asm volatile("s_waitcnt vmcnt(0)" ::: "memory")

  WVM4;  // K-tile 0 landed
  BAR;

#pragma unroll 1
  for (int it = 0; it < nk2 - 1; ++it) {
    const int j0 = 2 * it;
    SLOADA(0, 0); SLOADB(0); ST_A1(j0 + 1);
    BAR; WLG0; PRIO1; SMMA(0); PRIO0; BAR;
    SLOADA(1, 0); ST_A0(j0 + 2); ST_B(j0 + 2);
    BAR; WLG0; PRIO1; SMMA(1); PRIO0;
    WVM4;  // K-tile j0+1 landed
    BAR;
    SLOADA(0, 1); SLOADB(1); ST_A1(j0 + 2);
    BAR; WLG0; PRIO1; SMMA(0); PRIO0; BAR;
    SLOADA(1, 1); ST_A0(j0 + 3); ST_B(j0 + 3);
    BAR; WLG0; PRIO1; SMMA(1); PRIO0;
    WVM4;  // K-tile j0+2 landed
    BAR;
  }
  {  // tail: K-tiles 2*nk2-2 (buf0), 2*nk2-1 (buf1)
    SLOADA(0, 0); SLOADB(0); ST_A1(2 * nk2 - 1);
    BAR; WLG0; PRIO1; SMMA(0); PRIO0; BAR;
    SLOADA(1, 0);
    BAR; WLG0; PRIO1; SMMA(1); PRIO0;
    WVM0;  // drain (last K-tile complete)
    BAR;
    SLOADA(0, 1); SLOADB(1);
    BAR; WLG0; PRIO1; SMMA(0); PRIO0; BAR;
    SLOADA(1, 1);
    BAR; WLG0; PRIO1; SMMA(1); PRIO0; BAR;
  }

  // Epilogue: scale by 1/sums, stage fp32 [t 128][c 132] per c-half, store.
  float* ftile = (float*)lds;   // 128 x 132 fp32 = 67584 B (fits 96KB)
  const float* sumsb = sums + (size_t)b * 2048 + rt * 128;
  float* Ob = Out + (size_t)b * 2048 * 1024 + (size_t)(rt * 128) * 1024 +
              ct * 256;
  float iv[2];
#pragma unroll
  for (int j_ = 0; j_ < 2; ++j_)
    iv[j_] = 1.0f / sumsb[wc * 32 + j_ * 16 + l15];
#pragma unroll
  for (int qm = 0; qm < 2; ++qm) {
    if (qm) __syncthreads();
#pragma unroll
    for (int i_ = 0; i_ < 4; ++i_) {
      const int c0 = wr * 64 + i_ * 16 + quad * 4;
#pragma unroll
      for (int j_ = 0; j_ < 2; ++j_) {
        const int t = wc * 32 + j_ * 16 + l15;
        float4 v;
        v.x = acc[qm][i_][j_][0] * iv[j_];
        v.y = acc[qm][i_][j_][1] * iv[j_];
        v.z = acc[qm][i_][j_][2] * iv[j_];
        v.w = acc[qm][i_][j_][3] * iv[j_];
        *(float4*)(ftile + t * 132 + c0) = v;
      }
    }
    __syncthreads();
#pragma unroll
    for (int p = 0; p < 8; ++p) {
      const int row = p * 16 + (tid >> 5);
      const int c0f = (tid & 31) * 4;
      const float4 v = *(const float4*)(ftile + row * 132 + c0f);
      *(float4*)(Ob + (size_t)row * 1024 + qm * 128 + c0f) = v;
    }
  }
#undef ST_A0
#undef ST_A1
#undef ST_B
#undef SLOADA
#undef SLOADB
#undef SMMA
#undef BAR
#undef WLG0
#undef PRIO1
#undef PRIO0
#undef WVM4
#undef WVM0
}

// ---------------------------------------------------------------------------
extern "C" void kernel_launch(void* const* d_in, const int* in_sizes, int n_in,
                              void* d_out, int out_size, void* d_ws,
                              size_t ws_size, hipStream_t stream) {
  const float* x = (const float*)d_in[0];
  const float* wq = (const float*)d_in[1];
  const float* bq = (const float*)d_in[2];
  const float* wk = (const float*)d_in[3];
  const float* bk = (const float*)d_in[4];
  const float* wv = (const float*)d_in[5];
  const float* bv = (const float*)d_in[6];
  float* out = (float*)d_out;
  char* ws = (char*)d_ws;

  // Workspace layout (<=160 MB):
  //   [0,32M)      Qb bf16 [16384][1024]
  //   [32,64M)     Kb bf16 [16384][1024]
  //   [64,96M)     Vt bf16 [8][1024][2048]
  //   [96,130.1M)  Spk bf16 packed triangular [8][136*16384]
  //   [132,132.07M) sums fp32 [16384]
  //   [134,140M)   wb bf16 [3][1024][1024]
  //   xb (32MB @96M) aliases Spk: dead after qkv pass.
  u16* Qb = (u16*)(ws);
  u16* Kb = (u16*)(ws + ((size_t)32 << 20));
  u16* Vt = (u16*)(ws + ((size_t)64 << 20));
  u16* Spk = (u16*)(ws + ((size_t)96 << 20));
  u16* xb = (u16*)(ws + ((size_t)96 << 20));   // alias: dies before Spk written
  float* sums = (float*)(ws + ((size_t)132 << 20));
  u16* wb = (u16*)(ws + ((size_t)134 << 20));

  // pass 0: fused casts (x, wq/wk/wv) + sums zero-init, one dispatch
  cast_all_kernel<<<2048, 256, 0, stream>>>(x, wq, wk, wv, xb, wb, sums);

  // pass 1: fused Q,K,V projections (V transposed), 256^2 8-phase (r3)
  qkv_kernel<<<768, 512, 0, stream>>>(xb, wb, bq, bk, bv, Qb, Kb, Vt);

  // pass 2: causal exp-scores, 96KB 8-phase (r2-r4)
  score_kernel<<<576, 512, 0, stream>>>(Kb, Qb, Spk, sums);

  // pass 3: P @ V, 96KB 8-phase, balanced pairing (r4)
  pv_kernel<<<512, 512, 0, stream>>>(Spk, Vt, sums, out);
}

// Round 7
// 300.783 us; speedup vs baseline: 1.2014x; 1.0803x over previous
//
#include <hip/hip_runtime.h>
#include <stdint.h>

typedef unsigned short u16;
typedef __attribute__((ext_vector_type(8))) __bf16 bf16x8;
typedef __attribute__((ext_vector_type(4))) float f32x4;

#define DEVI __device__ __forceinline__

DEVI u16 f32_to_bf16(float f) {
  uint32_t u = __builtin_bit_cast(uint32_t, f);
  u += 0x7FFFu + ((u >> 16) & 1u);   // RNE; inputs are never NaN here
  return (u16)(u >> 16);
}

DEVI void gl2lds16(const void* g, void* l) {
  __builtin_amdgcn_global_load_lds(
      (const __attribute__((address_space(1))) void*)g,
      (__attribute__((address_space(3))) void*)l, 16, 0, 0);
}

// S is packed triangular: per batch, strip rt (128 rows) has row stride
// (rt+1)*128 and begins at tri(rt)*16384 u16.  Per-batch size 136*16384 u16.
#define S_BATCH 2228224  // u16 elements per batch = 136*16384

// ---------------------------------------------------------------------------
// Fused input casts: x (4M float4), weights (3x256K float4), sums zero-init.
// ---------------------------------------------------------------------------
__global__ void cast_all_kernel(const float* __restrict__ x,
                                const float* __restrict__ wq,
                                const float* __restrict__ wk,
                                const float* __restrict__ wv,
                                u16* __restrict__ xb, u16* __restrict__ wb,
                                float* __restrict__ sums) {
  const int i0 = blockIdx.x * blockDim.x + threadIdx.x;
  const int stride = gridDim.x * blockDim.x;   // 524288
  for (int j = i0; j < 4194304; j += stride) {  // x -> xb
    const float4 v = ((const float4*)x)[j];
    ushort4 o;
    o.x = f32_to_bf16(v.x);
    o.y = f32_to_bf16(v.y);
    o.z = f32_to_bf16(v.z);
    o.w = f32_to_bf16(v.w);
    ((ushort4*)xb)[j] = o;
  }
  for (int j = i0; j < 786432; j += stride) {   // wq|wk|wv -> wb
    const int z = j >> 18;
    const int r = j & 262143;
    const float* src = (z == 0) ? wq : (z == 1) ? wk : wv;
    const float4 v = ((const float4*)src)[r];
    ushort4 o;
    o.x = f32_to_bf16(v.x);
    o.y = f32_to_bf16(v.y);
    o.z = f32_to_bf16(v.z);
    o.w = f32_to_bf16(v.w);
    ((ushort4*)(wb + (size_t)z * 1048576))[r] = o;
  }
  if (i0 < 4096) ((float4*)sums)[i0] = (float4){0.f, 0.f, 0.f, 0.f};
}

// ---------------------------------------------------------------------------
// Fused Q/K/V projection — 256x256-tile, 8-wave, 8-phase schedule (T3+T4+T5).
// ROUND-3 VERSION, re-measured r5/r6: ~106.7 us / MfmaUtil 40.5%.  Do not
// touch: read-ahead (r2) and persistent (r4) variants both regressed.
// ---------------------------------------------------------------------------
__global__ __launch_bounds__(512, 2) void qkv_kernel(
    const u16* __restrict__ xb, const u16* __restrict__ wb,
    const float* __restrict__ bq, const float* __restrict__ bk,
    const float* __restrict__ bv, u16* __restrict__ Qb, u16* __restrict__ Kb,
    u16* __restrict__ Vt) {
  __shared__ __align__(16) u16 lds[65536];  // 128 KB

  const int id = blockIdx.x;                 // 0..767
  const int wg = (id & 7) * 96 + (id >> 3);  // bijective XCD swizzle (768%8==0)
  const int g = wg >> 3, u = wg & 7;         // groups of 8 tiles: 4c x 2t (~3MB L2)
  const int z = g >> 5;                      // 0..2
  const int tp = g & 31;                     // t-pair
  const int tmt = tp * 2 + (u >> 2);         // t-tile 0..63
  const int tct = u & 3;                     // c-tile 0..3

  // Q/K: A=W (m=c, reg-quad packs c); V: A=x (m=t, reg-quad packs t).
  int m0, n0;
  const u16* Aptr;
  const u16* Bptr;
  if (z < 2) {
    m0 = tct * 256;
    n0 = tmt * 256;
    Aptr = wb + (size_t)z * 1048576 + (size_t)m0 * 1024;
    Bptr = xb + (size_t)n0 * 1024;
  } else {
    m0 = tmt * 256;
    n0 = tct * 256;
    Aptr = xb + (size_t)m0 * 1024;
    Bptr = wb + (size_t)2 * 1048576 + (size_t)n0 * 1024;
  }

  const int tid = threadIdx.x;
  const int srow = tid >> 3;                 // staged row 0..63 (+64 2nd load)
  const int sgrp = ((tid & 7) - srow) & 7;   // rotated source column-group
  const u16* Ag = Aptr + (size_t)srow * 1024 + sgrp * 8;
  const u16* Bg = Bptr + (size_t)srow * 1024 + sgrp * 8;
  char* ldsDst = (char*)lds + tid * 16;

  // Half-tile stagers: 2 x gl_lds x 16B per thread = 128 rows x 64 cols bf16.
#define ST_A0(kt) do { const u16* s_ = Ag + (kt) * 64;           char* d_ = ldsDst + (((kt) & 1) * 65536);         gl2lds16(s_, d_); gl2lds16(s_ + 65536, d_ + 8192); } while (0)
#define ST_A1(kt) do { const u16* s_ = Ag + 131072 + (kt) * 64;  char* d_ = ldsDst + (((kt) & 1) * 65536) + 16384; gl2lds16(s_, d_); gl2lds16(s_ + 65536, d_ + 8192); } while (0)
#define ST_B0(kt) do { const u16* s_ = Bg + (kt) * 64;           char* d_ = ldsDst + (((kt) & 1) * 65536) + 32768; gl2lds16(s_, d_); gl2lds16(s_ + 65536, d_ + 8192); } while (0)
#define ST_B1(kt) do { const u16* s_ = Bg + 131072 + (kt) * 64;  char* d_ = ldsDst + (((kt) & 1) * 65536) + 49152; gl2lds16(s_, d_); gl2lds16(s_ + 65536, d_ + 8192); } while (0)

  // Prologue: K-tile 0 complete + A0/B0/B1 of K-tile 1 (7 half-tiles).
  ST_A0(0); ST_B0(0); ST_B1(0); ST_A1(0);
  ST_A0(1); ST_B0(1); ST_B1(1);

  const int lane = tid & 63, wid = tid >> 6;
  const int wr = wid >> 2, wc = wid & 3;
  const int l15 = lane & 15, quad = lane >> 4;

  int aoff[4][2], boff[2][2];
#pragma unroll
  for (int i_ = 0; i_ < 4; ++i_) {
    const int arow = wr * 64 + i_ * 16 + l15;
#pragma unroll
    for (int k_ = 0; k_ < 2; ++k_)
      aoff[i_][k_] = arow * 64 + ((k_ * 4 + quad + arow) & 7) * 8;
  }
#pragma unroll
  for (int j_ = 0; j_ < 2; ++j_) {
    const int brow = wc * 32 + j_ * 16 + l15;
#pragma unroll
    for (int k_ = 0; k_ < 2; ++k_)
      boff[j_][k_] = brow * 64 + ((k_ * 4 + quad + brow) & 7) * 8;
  }

  f32x4 acc[2][2][4][2];
#pragma unroll
  for (int a_ = 0; a_ < 2; ++a_)
#pragma unroll
    for (int b_ = 0; b_ < 2; ++b_)
#pragma unroll
      for (int i_ = 0; i_ < 4; ++i_)
#pragma unroll
        for (int j_ = 0; j_ < 2; ++j_)
          acc[a_][b_][i_][j_] = (f32x4){0.f, 0.f, 0.f, 0.f};

  bf16x8 af[4][2], bfr[2][2][2];

#define LOADA(qm, buf) do { const u16* p_ = lds + (buf) * 32768 + (qm) * 8192; \
  _Pragma("unroll") for (int i_ = 0; i_ < 4; ++i_) \
  _Pragma("unroll") for (int k_ = 0; k_ < 2; ++k_) \
    af[i_][k_] = *(const bf16x8*)(p_ + aoff[i_][k_]); } while (0)
#define LOADB(qn, buf) do { const u16* p_ = lds + (buf) * 32768 + 16384 + (qn) * 8192; \
  _Pragma("unroll") for (int j_ = 0; j_ < 2; ++j_) \
  _Pragma("unroll") for (int k_ = 0; k_ < 2; ++k_) \
    bfr[qn][j_][k_] = *(const bf16x8*)(p_ + boff[j_][k_]); } while (0)
#define MMA(qm, qn) do { \
  _Pragma("unroll") for (int i_ = 0; i_ < 4; ++i_) \
  _Pragma("unroll") for (int j_ = 0; j_ < 2; ++j_) \
  _Pragma("unroll") for (int k_ = 0; k_ < 2; ++k_) \
    acc[qm][qn][i_][j_] = __builtin_amdgcn_mfma_f32_16x16x32_bf16( \
        af[i_][k_], bfr[qn][j_][k_], acc[qm][qn][i_][j_], 0, 0, 0); } while (0)

#define BAR __builtin_amdgcn_s_barrier()
#define WLG0 asm volatile("s_waitcnt lgkmcnt(0)")
#define WLG8 asm volatile("s_waitcnt lgkmcnt(8)")
#define PRIO1 __builtin_amdgcn_s_setprio(1)
#define PRIO0 __builtin_amdgcn_s_setprio(0)
#define WVM6 asm volatile("s_waitcnt vmcnt(6)" ::: "memory")
#define WVM0 asm volatile("s_waitcnt vmcnt(0)" ::: "memory")

  WVM6;  // K-tile 0 landed
  BAR;

#pragma unroll 1
  for (int it = 0; it < 7; ++it) {
    const int j0 = 2 * it;
    // P1 (0,0) buf0
    LOADA(0, 0); LOADB(0, 0); ST_A1(j0 + 1); WLG8;
    BAR; WLG0; PRIO1; MMA(0, 0); PRIO0; BAR;
    // P2 (0,1)
    LOADB(1, 0); ST_A0(j0 + 2);
    BAR; WLG0; PRIO1; MMA(0, 1); PRIO0; BAR;
    // P3 (1,1)
    LOADA(1, 0); ST_B0(j0 + 2);
    BAR; WLG0; PRIO1; MMA(1, 1); PRIO0; BAR;
    // P4 (1,0)
    ST_B1(j0 + 2);
    BAR; PRIO1; MMA(1, 0); PRIO0;
    WVM6;  // K-tile j0+1 landed
    BAR;
    // P5 (0,0) buf1
    LOADA(0, 1); LOADB(0, 1); ST_A1(j0 + 2); WLG8;
    BAR; WLG0; PRIO1; MMA(0, 0); PRIO0; BAR;
    // P6 (0,1)
    LOADB(1, 1); ST_A0(j0 + 3);
    BAR; WLG0; PRIO1; MMA(0, 1); PRIO0; BAR;
    // P7 (1,1)
    LOADA(1, 1); ST_B0(j0 + 3);
    BAR; WLG0; PRIO1; MMA(1, 1); PRIO0; BAR;
    // P8 (1,0)
    ST_B1(j0 + 3);
    BAR; PRIO1; MMA(1, 0); PRIO0;
    WVM6;  // K-tile j0+2 landed
    BAR;
  }
  {  // it = 7: K-tiles 14 (buf0) / 15 (buf1); only A1(15) left to stage
    LOADA(0, 0); LOADB(0, 0); ST_A1(15); WLG8;
    BAR; WLG0; PRIO1; MMA(0, 0); PRIO0; BAR;
    LOADB(1, 0);
    BAR; WLG0; PRIO1; MMA(0, 1); PRIO0; BAR;
    LOADA(1, 0);
    BAR; WLG0; PRIO1; MMA(1, 1); PRIO0; BAR;
    BAR; PRIO1; MMA(1, 0); PRIO0;
    WVM0;  // drain: K-tile 15 landed
    BAR;
    LOADA(0, 1); LOADB(0, 1); WLG8;
    BAR; WLG0; PRIO1; MMA(0, 0); PRIO0; BAR;
    LOADB(1, 1);
    BAR; WLG0; PRIO1; MMA(0, 1); PRIO0; BAR;
    LOADA(1, 1);
    BAR; WLG0; PRIO1; MMA(1, 1); PRIO0; BAR;
    PRIO1; MMA(1, 0); PRIO0;
    BAR;  // mainloop done; LDS reusable
  }

  // Epilogue: per N-half th, stage [128 n-rows][256 m-cols] (+8 pad) in LDS,
  // then full-line 16B/lane global stores.
  if (z < 2) {
    const float* bias = (z == 0) ? bq : bk;
    u16* Out = (z == 0) ? Qb : Kb;
#pragma unroll
    for (int th = 0; th < 2; ++th) {
      if (th) __syncthreads();
#pragma unroll
      for (int qm = 0; qm < 2; ++qm)
#pragma unroll
        for (int i_ = 0; i_ < 4; ++i_) {
          const int c = qm * 128 + wr * 64 + i_ * 16 + quad * 4;
          const float4 b4 = *(const float4*)(bias + m0 + c);
#pragma unroll
          for (int j_ = 0; j_ < 2; ++j_) {
            const int row = wc * 32 + j_ * 16 + l15;
            ushort4 o;
            o.x = f32_to_bf16(acc[qm][th][i_][j_][0] + b4.x);
            o.y = f32_to_bf16(acc[qm][th][i_][j_][1] + b4.y);
            o.z = f32_to_bf16(acc[qm][th][i_][j_][2] + b4.z);
            o.w = f32_to_bf16(acc[qm][th][i_][j_][3] + b4.w);
            *(ushort4*)(lds + row * 264 + c) = o;   // [t][c]
          }
        }
      __syncthreads();
#pragma unroll
      for (int p = 0; p < 8; ++p) {
        const int row = p * 16 + (tid >> 5);
        const int c0 = (tid & 31) * 8;
        const uint4 v = *(const uint4*)(lds + row * 264 + c0);
        *(uint4*)(Out + (size_t)(n0 + th * 128 + row) * 1024 + m0 + c0) = v;
      }
    }
  } else {
    const int b = m0 >> 11;
    const int t0b = m0 & 2047;
    u16* Out = Vt + (size_t)b * 2097152;
#pragma unroll
    for (int th = 0; th < 2; ++th) {
      if (th) __syncthreads();
#pragma unroll
      for (int j_ = 0; j_ < 2; ++j_) {
        const int row = wc * 32 + j_ * 16 + l15;      // c within half
        const float bb = bv[n0 + th * 128 + row];
#pragma unroll
        for (int qm = 0; qm < 2; ++qm)
#pragma unroll
          for (int i_ = 0; i_ < 4; ++i_) {
            const int c = qm * 128 + wr * 64 + i_ * 16 + quad * 4;  // t
            ushort4 o;
            o.x = f32_to_bf16(acc[qm][th][i_][j_][0] + bb);
            o.y = f32_to_bf16(acc[qm][th][i_][j_][1] + bb);
            o.z = f32_to_bf16(acc[qm][th][i_][j_][2] + bb);
            o.w = f32_to_bf16(acc[qm][th][i_][j_][3] + bb);
            *(ushort4*)(lds + row * 264 + c) = o;     // [c][t]
          }
      }
      __syncthreads();
#pragma unroll
      for (int p = 0; p < 8; ++p) {
        const int row = p * 16 + (tid >> 5);
        const int c0 = (tid & 31) * 8;
        const uint4 v = *(const uint4*)(lds + row * 264 + c0);
        *(uint4*)(Out + (size_t)(n0 + th * 128 + row) * 2048 + t0b + c0) = v;
      }
    }
  }
#undef ST_A0
#undef ST_A1
#undef ST_B0
#undef ST_B1
#undef LOADA
#undef LOADB
#undef MMA
#undef BAR
#undef WLG0
#undef WLG8
#undef PRIO1
#undef PRIO0
#undef WVM6
#undef WVM0
}

// ---------------------------------------------------------------------------
// Scores — 192(s) x 128(t) tile, 8 waves, 3 phases/K-tile, 80KB LDS ->
// 2 blocks/CU (m114 inter-block stall overlap) with UNCHANGED prefetch
// distances (~5 phases; r5's failure was distance-1, avoided here).
// S[b][t][s] = exp((K.Q)/32), causal-masked, packed triangular (layout
// unchanged for pv).  A regions A0/A1/A2 = 64 s-rows each (one 8KB gl_lds
// call per region), B = 128 t-rows (2 calls); all double-buffered.
// Buf (u16): A0@0, A1@4096, A2@8192, B@12288; buf stride 20480 (40KB).
// Phase p computes s-rows [p*64,p*64+64); B read at P0, held in regs
// (B region dead after P0 -> ST_B(j+2) at P1 is >=1 barrier after readers).
// Staging: jP0: ST_A2(j+1); jP1: ST_A0(j+2)+ST_B(j+2); jP2: ST_A1(j+2).
// vmcnt ledger (simulated, steady 9 outstanding): end-of-phase waits
// WVM6/WVM8/WVM6; tail 14: WVM6/5/2, 15: WVM1/0.  Fragment:
//   s = p*64 + wr*32 + i*16 + quad*4 + r (i=0..1); t = wc*32 + j*16 + l15.
// Mask is a global compare (diagonal may cross TWO tiles at 192 granularity;
// also zeroes the harmless OOB-read tail of strip15/ct10 which lands in Kb).
// Grid 768 = 8 batches x 96 tiles (nt(rt)=ceil(2(rt+1)/3), sum=96).
// ---------------------------------------------------------------------------
__global__ __launch_bounds__(512, 4) void score_kernel(const u16* __restrict__ Kb,
                                                       const u16* __restrict__ Qb,
                                                       u16* __restrict__ Spk,
                                                       float* __restrict__ sums) {
  __shared__ __align__(16) u16 lds[40960];  // 80 KB

  const int id = blockIdx.x;   // 0..767
  const int b = id & 7;        // batch per XCD
  int rem = id >> 3;           // 0..95
  int rt = 0;
  for (;;) {
    const int n = (2 * rt + 4) / 3;   // nt(rt) = ceil(2(rt+1)/3)
    if (rem < n) break;
    rem -= n;
    ++rt;
  }
  const int ct = rem;                 // s-tile (192 cols each)
  const int sbase = ct * 192;
  const int tbase = rt * 128;

  const int tid = threadIdx.x;
  const int srow = tid >> 3;
  const int sgrp = ((tid & 7) - srow) & 7;
  const u16* A = Qb + ((size_t)b * 2048 + sbase) * 1024;   // 192 s-rows
  const u16* B = Kb + ((size_t)b * 2048 + tbase) * 1024;   // 128 t-rows
  const u16* Ag = A + (size_t)srow * 1024 + sgrp * 8;
  const u16* Bg = B + (size_t)srow * 1024 + sgrp * 8;
  char* ldsDst = (char*)lds + tid * 16;

  // One gl_lds call = 512 thr x 16B = 8KB = one 64-row region.
#define ST_A0(kt) gl2lds16(Ag + (kt) * 64,           ldsDst + ((kt) & 1) * 40960)
#define ST_A1(kt) gl2lds16(Ag + 65536 + (kt) * 64,   ldsDst + ((kt) & 1) * 40960 + 8192)
#define ST_A2(kt) gl2lds16(Ag + 131072 + (kt) * 64,  ldsDst + ((kt) & 1) * 40960 + 16384)
#define ST_B(kt)  do { const u16* s_ = Bg + (kt) * 64; char* d_ = ldsDst + ((kt) & 1) * 40960 + 24576; gl2lds16(s_, d_); gl2lds16(s_ + 65536, d_ + 8192); } while (0)

  // Prologue: tiles 0,1 minus A2(1) — queue [a0(0),b0,b0,a1(0),a2(0),
  // a0(1),b1,b1,a1(1)] = 9; WVM6 retires a0(0),b0,b0.
  ST_A0(0); ST_B(0); ST_A1(0); ST_A2(0);
  ST_A0(1); ST_B(1); ST_A1(1);

  const int lane = tid & 63, wid = tid >> 6;
  const int wr = wid >> 2, wc = wid & 3;
  const int l15 = lane & 15, quad = lane >> 4;

  int aoff[2][2], boff[2][2];
#pragma unroll
  for (int i_ = 0; i_ < 2; ++i_) {
    const int ar = wr * 32 + i_ * 16 + l15;    // region-local row 0..63
#pragma unroll
    for (int k_ = 0; k_ < 2; ++k_)
      aoff[i_][k_] = ar * 64 + ((k_ * 4 + quad + ar) & 7) * 8;
  }
#pragma unroll
  for (int j_ = 0; j_ < 2; ++j_) {
    const int brow = wc * 32 + j_ * 16 + l15;  // 0..127
#pragma unroll
    for (int k_ = 0; k_ < 2; ++k_)
      boff[j_][k_] = brow * 64 + ((k_ * 4 + quad + brow) & 7) * 8;
  }

  f32x4 acc[3][2][2];
#pragma unroll
  for (int p_ = 0; p_ < 3; ++p_)
#pragma unroll
    for (int i_ = 0; i_ < 2; ++i_)
#pragma unroll
      for (int j_ = 0; j_ < 2; ++j_)
        acc[p_][i_][j_] = (f32x4){0.f, 0.f, 0.f, 0.f};

  bf16x8 af[2][2], bfr[2][2];

#define SLA(p, buf) do { const u16* p_ = lds + (buf) * 20480 + (p) * 4096; \
  _Pragma("unroll") for (int i_ = 0; i_ < 2; ++i_) \
  _Pragma("unroll") for (int k_ = 0; k_ < 2; ++k_) \
    af[i_][k_] = *(const bf16x8*)(p_ + aoff[i_][k_]); } while (0)
#define SLB(buf) do { const u16* p_ = lds + (buf) * 20480 + 12288; \
  _Pragma("unroll") for (int j_ = 0; j_ < 2; ++j_) \
  _Pragma("unroll") for (int k_ = 0; k_ < 2; ++k_) \
    bfr[j_][k_] = *(const bf16x8*)(p_ + boff[j_][k_]); } while (0)
#define SMMA(p) do { \
  _Pragma("unroll") for (int i_ = 0; i_ < 2; ++i_) \
  _Pragma("unroll") for (int j_ = 0; j_ < 2; ++j_) \
  _Pragma("unroll") for (int k_ = 0; k_ < 2; ++k_) \
    acc[p][i_][j_] = __builtin_amdgcn_mfma_f32_16x16x32_bf16( \
        af[i_][k_], bfr[j_][k_], acc[p][i_][j_], 0, 0, 0); } while (0)

#define BAR __builtin_amdgcn_s_barrier()
#define WLG0 asm volatile("s_waitcnt lgkmcnt(0)")
#define PRIO1 __builtin_amdgcn_s_setprio(1)
#define PRIO0 __builtin_amdgcn_s_setprio(0)
#define WVM(n) asm volatile("s_waitcnt vmcnt(" #n ")" ::: "memory")

  WVM(6);  // a0(0), b(0) landed
  BAR;

#pragma unroll 1
  for (int it = 0; it < 7; ++it) {
    const int j0 = 2 * it;
    // ---- tile j0 (buf 0) ----
    SLA(0, 0); SLB(0); ST_A2(j0 + 1);
    BAR; WLG0; PRIO1; SMMA(0); PRIO0; WVM(6); BAR;
    SLA(1, 0); ST_A0(j0 + 2); ST_B(j0 + 2);
    BAR; WLG0; PRIO1; SMMA(1); PRIO0; WVM(8); BAR;
    SLA(2, 0); ST_A1(j0 + 2);
    BAR; WLG0; PRIO1; SMMA(2); PRIO0; WVM(6); BAR;
    // ---- tile j0+1 (buf 1) ----
    SLA(0, 1); SLB(1); ST_A2(j0 + 2);
    BAR; WLG0; PRIO1; SMMA(0); PRIO0; WVM(6); BAR;
    SLA(1, 1); ST_A0(j0 + 3); ST_B(j0 + 3);
    BAR; WLG0; PRIO1; SMMA(1); PRIO0; WVM(8); BAR;
    SLA(2, 1); ST_A1(j0 + 3);
    BAR; WLG0; PRIO1; SMMA(2); PRIO0; WVM(6); BAR;
  }
  {  // tail: tile 14 (buf0), tile 15 (buf1)
    SLA(0, 0); SLB(0); ST_A2(15);
    BAR; WLG0; PRIO1; SMMA(0); PRIO0; WVM(6); BAR;
    SLA(1, 0);
    BAR; WLG0; PRIO1; SMMA(1); PRIO0; WVM(5); BAR;
    SLA(2, 0);
    BAR; WLG0; PRIO1; SMMA(2); PRIO0; WVM(2); BAR;
    SLA(0, 1); SLB(1);
    BAR; WLG0; PRIO1; SMMA(0); PRIO0; WVM(1); BAR;
    SLA(1, 1);
    BAR; WLG0; PRIO1; SMMA(1); PRIO0; WVM(0); BAR;
    SLA(2, 1);
    BAR; WLG0; PRIO1; SMMA(2); PRIO0; BAR;
  }

  // Epilogue: exp + global-compare causal mask, row sums -> atomicAdd,
  // stage [t][s] 128x192 (stride 200) in LDS (50KB), store <=3 64-col panels.
  float sj[2] = {0.f, 0.f};
#pragma unroll
  for (int p_ = 0; p_ < 3; ++p_)
#pragma unroll
    for (int i_ = 0; i_ < 2; ++i_) {
      const int s0 = p_ * 64 + wr * 32 + i_ * 16 + quad * 4;
#pragma unroll
      for (int j_ = 0; j_ < 2; ++j_) {
        const int t = wc * 32 + j_ * 16 + l15;
        ushort4 o;
        float e[4];
#pragma unroll
        for (int r = 0; r < 4; ++r) {
          float v = __expf(acc[p_][i_][j_][r] * 0.03125f);
          if ((sbase + s0 + r) > (tbase + t)) v = 0.f;   // global causal mask
          e[r] = v;
          sj[j_] += v;
        }
        o.x = f32_to_bf16(e[0]);
        o.y = f32_to_bf16(e[1]);
        o.z = f32_to_bf16(e[2]);
        o.w = f32_to_bf16(e[3]);
        *(ushort4*)(lds + t * 200 + s0) = o;
      }
    }
#pragma unroll
  for (int j_ = 0; j_ < 2; ++j_) {
    float v = sj[j_];
    v += __shfl_xor(v, 16);
    v += __shfl_xor(v, 32);
    if (quad == 0)
      atomicAdd(&sums[(size_t)b * 2048 + tbase + wc * 32 + j_ * 16 + l15], v);
  }
  __syncthreads();
  const int ld = (rt + 1) * 128;
  const int nc = (ld - sbase < 192) ? (ld - sbase) : 192;  // 64/128/192
  u16* Out = Spk + (size_t)b * S_BATCH + (size_t)(rt * (rt + 1) / 2) * 16384 +
             sbase;
#pragma unroll
  for (int cp = 0; cp < 3; ++cp) {
    if (cp * 64 < nc) {
#pragma unroll
      for (int h = 0; h < 2; ++h) {
        const int row = h * 64 + (tid >> 3);
        const int c0 = cp * 64 + (tid & 7) * 8;
        const uint4 v = *(const uint4*)(lds + row * 200 + c0);
        *(uint4*)(Out + (size_t)row * ld + c0) = v;
      }
    }
  }
#undef ST_A0
#undef ST_A1
#undef ST_A2
#undef ST_B
#undef SLA
#undef SLB
#undef SMMA
#undef BAR
#undef WLG0
#undef PRIO1
#undef PRIO0
#undef WVM
}

// ---------------------------------------------------------------------------
// PV — 256(c) x 128(t) tile, 8 waves, 2 phases/K-tile, phase-head loads.
// 96KB LDS VERSION (r4/r6, known good).  Grid 512, 1 block/CU, 2 rounds;
// first 256 blocks rt 15..8 (heavy), second 256 rt 7..0 descending ->
// earliest-freed CUs take the heaviest queued blocks (~17 K-pairs/CU).
// out[b][t][c] = (1/sums[b][t]) * sum_s S[b][t][s] * Vt[b][c][s].
// ---------------------------------------------------------------------------
__global__ __launch_bounds__(512, 2) void pv_kernel(const u16* __restrict__ Spk,
                                                    const u16* __restrict__ Vt,
                                                    const float* __restrict__ sums,
                                                    float* __restrict__ Out) {
  __shared__ __align__(16) u16 lds[49152];  // 96 KB

  const int id = blockIdx.x;       // 0..511
  const int hf = id >> 8;
  const int rr_ = id & 255;
  const int rt = (hf ? 7 : 15) - (rr_ >> 5);   // balanced pairing (17/CU)
  const int ct = (rr_ >> 3) & 3;
  const int b = rr_ & 7;

  const int ldb = (rt + 1) * 128;
  const int nk2 = rt + 1;          // K-tile pairs; kIters = 2*nk2

  const int tid = threadIdx.x;
  const int srow = tid >> 3;
  const int sgrp = ((tid & 7) - srow) & 7;
  const u16* A = Vt + ((size_t)b * 1024 + ct * 256) * 2048;   // 256 c-rows
  const u16* B = Spk + (size_t)b * S_BATCH +
                 (size_t)(rt * (rt + 1) / 2) * 16384;         // 128 t-rows
  const u16* Ag = A + (size_t)srow * 2048 + sgrp * 8;
  const u16* Bg = B + (size_t)srow * ldb + sgrp * 8;
  char* ldsDst = (char*)lds + tid * 16;

#define ST_A0(kt) do { const u16* s_ = Ag + (kt) * 64;            char* d_ = ldsDst + (((kt) & 1) * 49152);         gl2lds16(s_, d_); gl2lds16(s_ + 131072, d_ + 8192); } while (0)
#define ST_A1(kt) do { const u16* s_ = Ag + 262144 + (kt) * 64;   char* d_ = ldsDst + (((kt) & 1) * 49152) + 16384; gl2lds16(s_, d_); gl2lds16(s_ + 131072, d_ + 8192); } while (0)
#define ST_B(kt)  do { const u16* s_ = Bg + (kt) * 64;            char* d_ = ldsDst + (((kt) & 1) * 49152) + 32768; gl2lds16(s_, d_); gl2lds16(s_ + (size_t)64 * ldb, d_ + 8192); } while (0)

  // Prologue: K-tile 0 complete + A0/B of K-tile 1.
  ST_A0(0); ST_B(0); ST_A1(0);
  ST_A0(1); ST_B(1);

  const int lane = tid & 63, wid = tid >> 6;
  const int wr = wid >> 2, wc = wid & 3;
  const int l15 = lane & 15, quad = lane >> 4;

  int aoff[4][2], boff[2][2];
#pragma unroll
  for (int i_ = 0; i_ < 4; ++i_) {
    const int arow = wr * 64 + i_ * 16 + l15;
#pragma unroll
    for (int k_ = 0; k_ < 2; ++k_)
      aoff[i_][k_] = arow * 64 + ((k_ * 4 + quad + arow) & 7) * 8;
  }
#pragma unroll
  for (int j_ = 0; j_ < 2; ++j_) {
    const int brow = wc * 32 + j_ * 16 + l15;
#pragma unroll
    for (int k_ = 0; k_ < 2; ++k_)
      boff[j_][k_] = brow * 64 + ((k_ * 4 + quad + brow) & 7) * 8;
  }

  f32x4 acc[2][4][2];
#pragma unroll
  for (int q_ = 0; q_ < 2; ++q_)
#pragma unroll
    for (int i_ = 0; i_ < 4; ++i_)
#pragma unroll
      for (int j_ = 0; j_ < 2; ++j_)
        acc[q_][i_][j_] = (f32x4){0.f, 0.f, 0.f, 0.f};

  bf16x8 af[4][2], bfr[2][2];

#define SLOADA(qm, buf) do { const u16* p_ = lds + (buf) * 24576 + (qm) * 8192; \
  _Pragma("unroll") for (int i_ = 0; i_ < 4; ++i_) \
  _Pragma("unroll") for (int k_ = 0; k_ < 2; ++k_) \
    af[i_][k_] = *(const bf16x8*)(p_ + aoff[i_][k_]); } while (0)
#define SLOADB(buf) do { const u16* p_ = lds + (buf) * 24576 + 16384; \
  _Pragma("unroll") for (int j_ = 0; j_ < 2; ++j_) \
  _Pragma("unroll") for (int k_ = 0; k_ < 2; ++k_) \
    bfr[j_][k_] = *(const bf16x8*)(p_ + boff[j_][k_]); } while (0)
#define SMMA(qm) do { \
  _Pragma("unroll") for (int i_ = 0; i_ < 4; ++i_) \
  _Pragma("unroll") for (int j_ = 0; j_ < 2; ++j_) \
  _Pragma("unroll") for (int k_ = 0; k_ < 2; ++k_) \
    acc[qm][i_][j_] = __builtin_amdgcn_mfma_f32_16x16x32_bf16( \
        af[i_][k_], bfr[j_][k_], acc[qm][i_][j_], 0, 0, 0); } while (0)

#define BAR __builtin_amdgcn_s_barrier()
#define WLG0 asm volatile("s_waitcnt lgkmcnt(0)")
#define PRIO1 __builtin_amdgcn_s_setprio(1)
#define PRIO0 __builtin_amdgcn_s_setprio(0)
#define WVM4 asm volatile("s_waitcnt vmcnt(4)" ::: "memory")
#define WVM0 asm volatile("s_waitcnt vmcnt(0)" ::: "memory")

  WVM4;  // K-tile 0 landed
  BAR;

#pragma unroll 1
  for (int it = 0; it < nk2 - 1; ++it) {
    const int j0 = 2 * it;
    SLOADA(0, 0); SLOADB(0); ST_A1(j0 + 1);
    BAR; WLG0; PRIO1; SMMA(0); PRIO0; BAR;
    SLOADA(1, 0); ST_A0(j0 + 2); ST_B(j0 + 2);
    BAR; WLG0; PRIO1; SMMA(1); PRIO0;
    WVM4;  // K-tile j0+1 landed
    BAR;
    SLOADA(0, 1); SLOADB(1); ST_A1(j0 + 2);
    BAR; WLG0; PRIO1; SMMA(0); PRIO0; BAR;
    SLOADA(1, 1); ST_A0(j0 + 3); ST_B(j0 + 3);
    BAR; WLG0; PRIO1; SMMA(1); PRIO0;
    WVM4;  // K-tile j0+2 landed
    BAR;
  }
  {  // tail: K-tiles 2*nk2-2 (buf0), 2*nk2-1 (buf1)
    SLOADA(0, 0); SLOADB(0); ST_A1(2 * nk2 - 1);
    BAR; WLG0; PRIO1; SMMA(0); PRIO0; BAR;
    SLOADA(1, 0);
    BAR; WLG0; PRIO1; SMMA(1); PRIO0;
    WVM0;  // drain (last K-tile complete)
    BAR;
    SLOADA(0, 1); SLOADB(1);
    BAR; WLG0; PRIO1; SMMA(0); PRIO0; BAR;
    SLOADA(1, 1);
    BAR; WLG0; PRIO1; SMMA(1); PRIO0; BAR;
  }

  // Epilogue: scale by 1/sums, stage fp32 [t 128][c 132] per c-half, store.
  float* ftile = (float*)lds;   // 128 x 132 fp32 = 67584 B (fits 96KB)
  const float* sumsb = sums + (size_t)b * 2048 + rt * 128;
  float* Ob = Out + (size_t)b * 2048 * 1024 + (size_t)(rt * 128) * 1024 +
              ct * 256;
  float iv[2];
#pragma unroll
  for (int j_ = 0; j_ < 2; ++j_)
    iv[j_] = 1.0f / sumsb[wc * 32 + j_ * 16 + l15];
#pragma unroll
  for (int qm = 0; qm < 2; ++qm) {
    if (qm) __syncthreads();
#pragma unroll
    for (int i_ = 0; i_ < 4; ++i_) {
      const int c0 = wr * 64 + i_ * 16 + quad * 4;
#pragma unroll
      for (int j_ = 0; j_ < 2; ++j_) {
        const int t = wc * 32 + j_ * 16 + l15;
        float4 v;
        v.x = acc[qm][i_][j_][0] * iv[j_];
        v.y = acc[qm][i_][j_][1] * iv[j_];
        v.z = acc[qm][i_][j_][2] * iv[j_];
        v.w = acc[qm][i_][j_][3] * iv[j_];
        *(float4*)(ftile + t * 132 + c0) = v;
      }
    }
    __syncthreads();
#pragma unroll
    for (int p = 0; p < 8; ++p) {
      const int row = p * 16 + (tid >> 5);
      const int c0f = (tid & 31) * 4;
      const float4 v = *(const float4*)(ftile + row * 132 + c0f);
      *(float4*)(Ob + (size_t)row * 1024 + qm * 128 + c0f) = v;
    }
  }
#undef ST_A0
#undef ST_A1
#undef ST_B
#undef SLOADA
#undef SLOADB
#undef SMMA
#undef BAR
#undef WLG0
#undef PRIO1
#undef PRIO0
#undef WVM4
#undef WVM0
}

// ---------------------------------------------------------------------------
extern "C" void kernel_launch(void* const* d_in, const int* in_sizes, int n_in,
                              void* d_out, int out_size, void* d_ws,
                              size_t ws_size, hipStream_t stream) {
  const float* x = (const float*)d_in[0];
  const float* wq = (const float*)d_in[1];
  const float* bq = (const float*)d_in[2];
  const float* wk = (const float*)d_in[3];
  const float* bk = (const float*)d_in[4];
  const float* wv = (const float*)d_in[5];
  const float* bv = (const float*)d_in[6];
  float* out = (float*)d_out;
  char* ws = (char*)d_ws;

  // Workspace layout (<=160 MB):
  //   [0,32M)      Qb bf16 [16384][1024]
  //   [32,64M)     Kb bf16 [16384][1024]
  //   [64,96M)     Vt bf16 [8][1024][2048]
  //   [96,130.1M)  Spk bf16 packed triangular [8][136*16384]
  //   [132,132.07M) sums fp32 [16384]
  //   [134,140M)   wb bf16 [3][1024][1024]
  //   xb (32MB @96M) aliases Spk: dead after qkv pass.
  u16* Qb = (u16*)(ws);
  u16* Kb = (u16*)(ws + ((size_t)32 << 20));
  u16* Vt = (u16*)(ws + ((size_t)64 << 20));
  u16* Spk = (u16*)(ws + ((size_t)96 << 20));
  u16* xb = (u16*)(ws + ((size_t)96 << 20));   // alias: dies before Spk written
  float* sums = (float*)(ws + ((size_t)132 << 20));
  u16* wb = (u16*)(ws + ((size_t)134 << 20));

  // pass 0: fused casts (x, wq/wk/wv) + sums zero-init, one dispatch
  cast_all_kernel<<<2048, 256, 0, stream>>>(x, wq, wk, wv, xb, wb, sums);

  // pass 1: fused Q,K,V projections (V transposed), 256^2 8-phase (r3)
  qkv_kernel<<<768, 512, 0, stream>>>(xb, wb, bq, bk, bv, Qb, Kb, Vt);

  // pass 2: causal exp-scores, 192x128-tile, 80KB -> 2 blocks/CU
  score_kernel<<<768, 512, 0, stream>>>(Kb, Qb, Spk, sums);

  // pass 3: P @ V, 96KB 8-phase, balanced pairing (r4/r6)
  pv_kernel<<<512, 512, 0, stream>>>(Spk, Vt, sums, out);
}